// Round 1
// baseline (1753.569 us; speedup 1.0000x reference)
//
#include <hip/hip_runtime.h>

// ---------------------------------------------------------------------------
// DGI forward: 2-layer GCN encoder (pos + permuted neg), summary, bilinear disc.
// Strategy: device-built CSR (by dst) -> gather-based aggregation (no float
// atomics); f32 tiled GEMM (64x64x16, 256 thr, 4x4 microtile) for h@W.
// ---------------------------------------------------------------------------

__global__ void k_degree(const int* __restrict__ dst, int* __restrict__ deg, int E) {
    int e = blockIdx.x * blockDim.x + threadIdx.x;
    if (e < E) atomicAdd(&deg[dst[e]], 1);
}

__global__ void k_dinv(const int* __restrict__ deg, float* __restrict__ dinv,
                       int* __restrict__ rowptr, int N, int E) {
    int n = blockIdx.x * blockDim.x + threadIdx.x;
    if (n < N) dinv[n] = 1.0f / sqrtf(1.0f + (float)deg[n]);
    if (n == 0) rowptr[N] = E;
}

// exclusive scan: 1024 elems/block, 256 threads x 4
__global__ void k_scanA(const int* __restrict__ in, int* __restrict__ out,
                        int* __restrict__ bsum, int n) {
    __shared__ int sh[256];
    int t = threadIdx.x;
    int base = blockIdx.x * 1024 + t * 4;
    int v[4];
#pragma unroll
    for (int j = 0; j < 4; ++j) v[j] = (base + j < n) ? in[base + j] : 0;
    int s = v[0] + v[1] + v[2] + v[3];
    sh[t] = s;
    __syncthreads();
    for (int off = 1; off < 256; off <<= 1) {
        int u = (t >= off) ? sh[t - off] : 0;
        __syncthreads();
        sh[t] += u;
        __syncthreads();
    }
    int excl = sh[t] - s;
    if (t == 255) bsum[blockIdx.x] = sh[255];
    int run = excl;
#pragma unroll
    for (int j = 0; j < 4; ++j) {
        if (base + j < n) out[base + j] = run;
        run += v[j];
    }
}

__global__ void k_scanB(const int* __restrict__ bsum, int* __restrict__ boff, int nb) {
    __shared__ int sh[128];
    int t = threadIdx.x;
    int v = (t < nb) ? bsum[t] : 0;
    sh[t] = v;
    __syncthreads();
    for (int off = 1; off < 128; off <<= 1) {
        int u = (t >= off) ? sh[t - off] : 0;
        __syncthreads();
        sh[t] += u;
        __syncthreads();
    }
    boff[t] = sh[t] - v;
}

__global__ void k_scanC(int* __restrict__ out, const int* __restrict__ boff, int n) {
    int t = threadIdx.x;
    int base = blockIdx.x * 1024 + t * 4;
    int add = boff[blockIdx.x];
#pragma unroll
    for (int j = 0; j < 4; ++j)
        if (base + j < n) out[base + j] += add;
}

__global__ void k_fill(const int* __restrict__ src, const int* __restrict__ dst,
                       const int* __restrict__ rowptr, int* __restrict__ cursor,
                       int* __restrict__ csr, int E) {
    int e = blockIdx.x * blockDim.x + threadIdx.x;
    if (e >= E) return;
    int d = dst[e];
    int p = rowptr[d] + atomicAdd(&cursor[d], 1);
    csr[p] = src[e];
}

// C[M,Nc] = A[M,K] @ B[K,Nc]; rowmap gathers A rows if non-null.
// BM=BN=64, BK=16, 256 threads, 4x4 per thread.
__global__ __launch_bounds__(256) void k_gemm(
        const float* __restrict__ A, const float* __restrict__ B,
        float* __restrict__ C, const int* __restrict__ rowmap,
        int M, int K, int Nc) {
    __shared__ float As[16][68];
    __shared__ float Bs[16][68];
    int tid = threadIdx.x;
    int row0 = blockIdx.y * 64, col0 = blockIdx.x * 64;
    int tx = tid & 15, ty = tid >> 4;
    float acc[4][4];
#pragma unroll
    for (int i = 0; i < 4; ++i)
#pragma unroll
        for (int j = 0; j < 4; ++j) acc[i][j] = 0.f;

    int ar = tid >> 2;              // 0..63 row in tile
    int ak = (tid & 3) << 2;        // 0..12 k offset
    int arow = row0 + ar;
    const float* Arow = nullptr;
    if (arow < M) {
        int sr = rowmap ? rowmap[arow] : arow;
        Arow = A + (size_t)sr * K;
    }
    int bkk = tid >> 4;             // 0..15 k row
    int bn = (tid & 15) << 2;       // 0..60 col offset

    for (int k0 = 0; k0 < K; k0 += 16) {
        float4 av = make_float4(0.f, 0.f, 0.f, 0.f);
        if (Arow) av = *(const float4*)(Arow + k0 + ak);
        float4 bv = *(const float4*)(B + (size_t)(k0 + bkk) * Nc + col0 + bn);
        __syncthreads();
        As[ak + 0][ar] = av.x;
        As[ak + 1][ar] = av.y;
        As[ak + 2][ar] = av.z;
        As[ak + 3][ar] = av.w;
        *(float4*)&Bs[bkk][bn] = bv;
        __syncthreads();
#pragma unroll
        for (int kk = 0; kk < 16; ++kk) {
            float4 a = *(const float4*)&As[kk][ty * 4];
            float4 b = *(const float4*)&Bs[kk][tx * 4];
            float af[4] = {a.x, a.y, a.z, a.w};
            float bf[4] = {b.x, b.y, b.z, b.w};
#pragma unroll
            for (int i = 0; i < 4; ++i)
#pragma unroll
                for (int j = 0; j < 4; ++j) acc[i][j] += af[i] * bf[j];
        }
    }
#pragma unroll
    for (int i = 0; i < 4; ++i) {
        int r = row0 + ty * 4 + i;
        if (r < M) {
            float4 v = make_float4(acc[i][0], acc[i][1], acc[i][2], acc[i][3]);
            *(float4*)(C + (size_t)r * Nc + col0 + tx * 4) = v;
        }
    }
}

// out[n,:] = (relu?) dinv[n]*sum_{s in csr row} dinv[s]*hw[s,:] + dinv[n]^2*hw[n,:] + b
template <int F>
__global__ __launch_bounds__(256) void k_aggregate(
        const float* __restrict__ hw, const int* __restrict__ rowptr,
        const int* __restrict__ csr, const float* __restrict__ dinv,
        const float* __restrict__ bias, float* __restrict__ out,
        int n, int relu) {
    constexpr int NF = F / 64;
    int wid = (blockIdx.x * blockDim.x + threadIdx.x) >> 6;
    int lane = threadIdx.x & 63;
    if (wid >= n) return;
    float dn = dinv[wid];
    int beg = rowptr[wid], end = rowptr[wid + 1];
    int off = lane * NF;
    float acc[NF];
#pragma unroll
    for (int i = 0; i < NF; ++i) acc[i] = 0.f;
    for (int e = beg; e < end; ++e) {
        int s = csr[e];
        float w = dinv[s];
        const float* row = hw + (size_t)s * F + off;
        if constexpr (NF == 4) {
            float4 v = *(const float4*)row;
            acc[0] += w * v.x; acc[1] += w * v.y;
            acc[2] += w * v.z; acc[3] += w * v.w;
        } else {
            float2 v = *(const float2*)row;
            acc[0] += w * v.x; acc[1] += w * v.y;
        }
    }
    float sw = dn * dn;
    const float* my = hw + (size_t)wid * F + off;
    float* o = out + (size_t)wid * F + off;
    float res[NF];
#pragma unroll
    for (int i = 0; i < NF; ++i) {
        float v = dn * acc[i] + sw * my[i] + bias[off + i];
        res[i] = relu ? fmaxf(v, 0.f) : v;
    }
    if constexpr (NF == 4) {
        *(float4*)o = make_float4(res[0], res[1], res[2], res[3]);
    } else {
        *(float2*)o = make_float2(res[0], res[1]);
    }
}

__global__ void k_colsum(const float* __restrict__ H, float* __restrict__ colsum, int n) {
    int c = threadIdx.x & 127, half = threadIdx.x >> 7;
    float acc = 0.f;
    for (int r = blockIdx.x * 2 + half; r < n; r += gridDim.x * 2)
        acc += H[(size_t)r * 128 + c];
    __shared__ float sh[256];
    sh[threadIdx.x] = acc;
    __syncthreads();
    if (half == 0) atomicAdd(&colsum[c], sh[c] + sh[c + 128]);
}

// t = Wb @ sigmoid(colsum / n)
__global__ void k_summary(const float* __restrict__ colsum, const float* __restrict__ Wb,
                          float* __restrict__ t, int n) {
    __shared__ float s_sh[128];
    int d = threadIdx.x;
    float m = colsum[d] / (float)n;
    s_sh[d] = 1.0f / (1.0f + expf(-m));
    __syncthreads();
    float acc = 0.f;
    for (int e = 0; e < 128; ++e) acc += Wb[d * 128 + e] * s_sh[e];
    t[d] = acc;
}

// score[n] = dot(H[n,:], t) + bb  (one wave per node)
__global__ void k_disc(const float* __restrict__ H, const float* __restrict__ t,
                       const float* __restrict__ bb, float* __restrict__ out, int n) {
    int wid = (blockIdx.x * blockDim.x + threadIdx.x) >> 6;
    int lane = threadIdx.x & 63;
    if (wid >= n) return;
    const float* row = H + (size_t)wid * 128;
    float p = row[lane] * t[lane] + row[lane + 64] * t[lane + 64];
#pragma unroll
    for (int off = 32; off > 0; off >>= 1) p += __shfl_down(p, off);
    if (lane == 0) out[wid] = p + bb[0];
}

extern "C" void kernel_launch(void* const* d_in, const int* in_sizes, int n_in,
                              void* d_out, int out_size, void* d_ws, size_t ws_size,
                              hipStream_t stream) {
    const float* x    = (const float*)d_in[0];
    const int*   ei   = (const int*)d_in[1];
    const int*   perm = (const int*)d_in[2];
    const float* W1   = (const float*)d_in[3];
    const float* b1   = (const float*)d_in[4];
    const float* W2   = (const float*)d_in[5];
    const float* b2   = (const float*)d_in[6];
    const float* Wb   = (const float*)d_in[7];
    const float* bb   = (const float*)d_in[8];
    float* out = (float*)d_out;

    const int N   = in_sizes[2];
    const int E   = in_sizes[1] / 2;
    const int IN  = in_sizes[0] / N;   // 256
    const int HID = in_sizes[4];       // 256
    const int OUT = in_sizes[6];       // 128
    const int* src = ei;
    const int* dst = ei + E;

    char* p = (char*)d_ws;
    auto alloc = [&](size_t bytes) -> void* {
        void* r = (void*)p;
        p += (bytes + 255) & ~(size_t)255;
        return r;
    };
    int*   deg    = (int*)alloc((size_t)N * 4);
    int*   cursor = (int*)alloc((size_t)N * 4);
    float* colsum = (float*)alloc(128 * 4);
    size_t zlen   = (size_t)(p - (char*)deg);     // deg+cursor+colsum zeroed together
    int*   rowptr = (int*)alloc((size_t)(N + 1) * 4);
    int*   bsum   = (int*)alloc(128 * 4);
    int*   boff   = (int*)alloc(128 * 4);
    int*   csr    = (int*)alloc((size_t)E * 4);
    float* dinv   = (float*)alloc((size_t)N * 4);
    float* tvec   = (float*)alloc(128 * 4);
    float* bufA   = (float*)alloc((size_t)N * 256 * 4);
    float* bufB   = (float*)alloc((size_t)N * 256 * 4);
    float* bufC   = (float*)alloc((size_t)N * 128 * 4);

    hipMemsetAsync(deg, 0, zlen, stream);

    int eb = (E + 255) / 256;
    int nb = (N + 255) / 256;
    int nscan = (N + 1023) / 1024;
    k_degree<<<eb, 256, 0, stream>>>(dst, deg, E);
    k_dinv<<<nb, 256, 0, stream>>>(deg, dinv, rowptr, N, E);
    k_scanA<<<nscan, 256, 0, stream>>>(deg, rowptr, bsum, N);
    k_scanB<<<1, 128, 0, stream>>>(bsum, boff, nscan);
    k_scanC<<<nscan, 256, 0, stream>>>(rowptr, boff, N);
    k_fill<<<eb, 256, 0, stream>>>(src, dst, rowptr, cursor, csr, E);

    dim3 g1(HID / 64, (N + 63) / 64);
    dim3 g2(OUT / 64, (N + 63) / 64);
    int aggb = (N + 3) / 4;            // 4 waves (nodes) per 256-thr block

    // positive encode: H_pos -> bufC
    k_gemm<<<g1, 256, 0, stream>>>(x, W1, bufA, nullptr, N, IN, HID);
    k_aggregate<256><<<aggb, 256, 0, stream>>>(bufA, rowptr, csr, dinv, b1, bufB, N, 1);
    k_gemm<<<g2, 256, 0, stream>>>(bufB, W2, bufA, nullptr, N, HID, OUT);
    k_aggregate<128><<<aggb, 256, 0, stream>>>(bufA, rowptr, csr, dinv, b2, bufC, N, 0);
    k_colsum<<<256, 256, 0, stream>>>(bufC, colsum, N);

    // negative encode: H_neg -> bufB (reuse)
    k_gemm<<<g1, 256, 0, stream>>>(x, W1, bufA, perm, N, IN, HID);
    k_aggregate<256><<<aggb, 256, 0, stream>>>(bufA, rowptr, csr, dinv, b1, bufB, N, 1);
    k_gemm<<<g2, 256, 0, stream>>>(bufB, W2, bufA, nullptr, N, HID, OUT);
    k_aggregate<128><<<aggb, 256, 0, stream>>>(bufA, rowptr, csr, dinv, b2, bufB, N, 0);

    // summary + discriminator
    k_summary<<<1, 128, 0, stream>>>(colsum, Wb, tvec, N);
    int db = ((size_t)N * 64 + 255) / 256;
    k_disc<<<db, 256, 0, stream>>>(bufC, tvec, bb, out, N);
    k_disc<<<db, 256, 0, stream>>>(bufB, tvec, bb, out + N, N);
}

// Round 2
// 1437.413 us; speedup vs baseline: 1.2199x; 1.2199x over previous
//
#include <hip/hip_runtime.h>

// ---------------------------------------------------------------------------
// DGI forward, round 2:
//  - neg layer-1 GEMM eliminated via (x@W1)[perm] == x[perm]@W1
//  - GEMMs via split-bf16 MFMA (hi*hi + hi*lo + lo*hi), 16x16x32, 128x128 tile
//  - fused pos+neg layer-1 aggregate with relu + bf16 hi/lo split epilogue
// ---------------------------------------------------------------------------

typedef __attribute__((ext_vector_type(8))) short bh8;     // 8 bf16 (4 VGPR)
typedef __attribute__((ext_vector_type(4))) float f4;      // MFMA acc
typedef __attribute__((ext_vector_type(4))) unsigned short u16x4;

#define AS1 __attribute__((address_space(1)))
#define AS3 __attribute__((address_space(3)))

__device__ __forceinline__ unsigned short f2b(float f) {   // f32 -> bf16 RTNE
    unsigned int u = __float_as_uint(f);
    unsigned int r = (u + 0x7FFFu + ((u >> 16) & 1u)) >> 16;
    return (unsigned short)r;
}
__device__ __forceinline__ float b2f(unsigned short h) {
    return __uint_as_float(((unsigned int)h) << 16);
}

// ----------------------------- CSR build -----------------------------------
__global__ void k_degree(const int* __restrict__ dst, int* __restrict__ deg, int E) {
    int e = blockIdx.x * blockDim.x + threadIdx.x;
    if (e < E) atomicAdd(&deg[dst[e]], 1);
}

__global__ void k_dinv(const int* __restrict__ deg, float* __restrict__ dinv,
                       int* __restrict__ rowptr, int N, int E) {
    int n = blockIdx.x * blockDim.x + threadIdx.x;
    if (n < N) dinv[n] = 1.0f / sqrtf(1.0f + (float)deg[n]);
    if (n == 0) rowptr[N] = E;
}

__global__ void k_scanA(const int* __restrict__ in, int* __restrict__ out,
                        int* __restrict__ bsum, int n) {
    __shared__ int sh[256];
    int t = threadIdx.x;
    int base = blockIdx.x * 1024 + t * 4;
    int v[4];
#pragma unroll
    for (int j = 0; j < 4; ++j) v[j] = (base + j < n) ? in[base + j] : 0;
    int s = v[0] + v[1] + v[2] + v[3];
    sh[t] = s;
    __syncthreads();
    for (int off = 1; off < 256; off <<= 1) {
        int u = (t >= off) ? sh[t - off] : 0;
        __syncthreads();
        sh[t] += u;
        __syncthreads();
    }
    int excl = sh[t] - s;
    if (t == 255) bsum[blockIdx.x] = sh[255];
    int run = excl;
#pragma unroll
    for (int j = 0; j < 4; ++j) {
        if (base + j < n) out[base + j] = run;
        run += v[j];
    }
}

__global__ void k_scanB(const int* __restrict__ bsum, int* __restrict__ boff, int nb) {
    __shared__ int sh[128];
    int t = threadIdx.x;
    int v = (t < nb) ? bsum[t] : 0;
    sh[t] = v;
    __syncthreads();
    for (int off = 1; off < 128; off <<= 1) {
        int u = (t >= off) ? sh[t - off] : 0;
        __syncthreads();
        sh[t] += u;
        __syncthreads();
    }
    boff[t] = sh[t] - v;
}

__global__ void k_scanC(int* __restrict__ out, const int* __restrict__ boff, int n) {
    int t = threadIdx.x;
    int base = blockIdx.x * 1024 + t * 4;
    int add = boff[blockIdx.x];
#pragma unroll
    for (int j = 0; j < 4; ++j)
        if (base + j < n) out[base + j] += add;
}

__global__ void k_fill(const int* __restrict__ src, const int* __restrict__ dst,
                       const int* __restrict__ rowptr, int* __restrict__ cursor,
                       int* __restrict__ csr, int E) {
    int e = blockIdx.x * blockDim.x + threadIdx.x;
    if (e >= E) return;
    int d = dst[e];
    int p = rowptr[d] + atomicAdd(&cursor[d], 1);
    csr[p] = src[e];
}

// ------------------------- f32 -> bf16 hi/lo split --------------------------
__global__ void k_split(const float* __restrict__ in, unsigned short* __restrict__ hi,
                        unsigned short* __restrict__ lo, long n4) {
    long i = (long)blockIdx.x * blockDim.x + threadIdx.x;
    if (i >= n4) return;
    float4 v = ((const float4*)in)[i];
    float f[4] = {v.x, v.y, v.z, v.w};
    u16x4 h, l;
#pragma unroll
    for (int j = 0; j < 4; ++j) {
        unsigned short hb = f2b(f[j]);
        h[j] = hb;
        l[j] = f2b(f[j] - b2f(hb));
    }
    ((u16x4*)hi)[i] = h;
    ((u16x4*)lo)[i] = l;
}

// W [K][Nc] f32 -> Wt_hi/lo [Nc][K] bf16 (transpose + split); tiny matrices
__global__ void k_wsplitT(const float* __restrict__ W, unsigned short* __restrict__ thi,
                          unsigned short* __restrict__ tlo, int K, int Nc) {
    int t = blockIdx.x * blockDim.x + threadIdx.x;
    if (t >= K * Nc) return;
    int k = t / Nc, n = t % Nc;
    float f = W[t];
    unsigned short hb = f2b(f);
    thi[n * K + k] = hb;
    tlo[n * K + k] = f2b(f - b2f(hb));
}

// --------------------- split-bf16 MFMA GEMM (C = A@B) -----------------------
// A planes [M][K] bf16 hi/lo, B planes [Nc][K] bf16 hi/lo (pre-transposed).
// BM=BN=128, BK=32, 256 threads (4 waves, 2x2 of 64x64 wave tiles).
__global__ __launch_bounds__(256, 2) void k_gemm_mfma(
        const unsigned short* __restrict__ Ahi, const unsigned short* __restrict__ Alo,
        const unsigned short* __restrict__ Bhi, const unsigned short* __restrict__ Blo,
        float* __restrict__ C, int M, int K, int Nc) {
    __shared__ short lds[4][128 * 32];          // planes: Ahi, Alo, Bhi, Blo (32 KB)
    const int tid  = threadIdx.x;
    const int lane = tid & 63;
    const int w    = tid >> 6;                  // wave 0..3
    const int wr   = w >> 1, wc = w & 1;
    const int row0 = blockIdx.y * 128;
    const int col0 = blockIdx.x * 128;

    // this wave stages plane w (8 slabs of 16 rows, global_load_lds width=16)
    const unsigned short* sp = (w == 0) ? Ahi : (w == 1) ? Alo : (w == 2) ? Bhi : Blo;
    const int  base0 = (w < 2) ? row0 : col0;
    const int  lim   = (w < 2) ? (M - 1) : (Nc - 1);
    const int  rsub  = lane >> 2;               // 0..15 row within slab
    const int  clin  = lane & 3;                // 16B chunk within 64B row

    f4 acc[4][4] = {};

    for (int k0 = 0; k0 < K; k0 += 32) {
        __syncthreads();                        // prev-step LDS reads done
#pragma unroll
        for (int s = 0; s < 8; ++s) {
            int r = s * 16 + rsub;              // tile row 0..127
            int g = base0 + r;
            if (g > lim) g = lim;               // tail clamp (rows >= M unused)
            const unsigned short* src = sp + (size_t)g * K + k0 + clin * 8;
            __builtin_amdgcn_global_load_lds((const AS1 void*)src,
                                             (AS3 void*)&lds[w][s * 512], 16, 0, 0);
        }
        __syncthreads();                        // drains vmcnt; staging visible

        // fragments: row/col = lane&15, k-chunk = lane>>4 (covers BK=32)
        bh8 ah[4], al[4], bh_[4], bl[4];
        const int fr = lane & 15;
        const int fc = (lane >> 4) * 8;         // element offset within row
#pragma unroll
        for (int m = 0; m < 4; ++m) {
            int off = (wr * 64 + m * 16 + fr) * 32 + fc;
            ah[m] = *(const bh8*)&lds[0][off];
            al[m] = *(const bh8*)&lds[1][off];
        }
#pragma unroll
        for (int n = 0; n < 4; ++n) {
            int off = (wc * 64 + n * 16 + fr) * 32 + fc;
            bh_[n] = *(const bh8*)&lds[2][off];
            bl[n]  = *(const bh8*)&lds[3][off];
        }
#pragma unroll
        for (int m = 0; m < 4; ++m)
#pragma unroll
            for (int n = 0; n < 4; ++n)
                acc[m][n] = __builtin_amdgcn_mfma_f32_16x16x32_bf16(ah[m], bh_[n], acc[m][n], 0, 0, 0);
#pragma unroll
        for (int m = 0; m < 4; ++m)
#pragma unroll
            for (int n = 0; n < 4; ++n)
                acc[m][n] = __builtin_amdgcn_mfma_f32_16x16x32_bf16(ah[m], bl[n], acc[m][n], 0, 0, 0);
#pragma unroll
        for (int m = 0; m < 4; ++m)
#pragma unroll
            for (int n = 0; n < 4; ++n)
                acc[m][n] = __builtin_amdgcn_mfma_f32_16x16x32_bf16(al[m], bh_[n], acc[m][n], 0, 0, 0);
    }

    // epilogue: C/D layout col=lane&15, row=(lane>>4)*4+reg  [verified]
    const int cr = (lane >> 4) * 4;
    const int cc = lane & 15;
#pragma unroll
    for (int m = 0; m < 4; ++m) {
        int r0 = row0 + wr * 64 + m * 16 + cr;
#pragma unroll
        for (int n = 0; n < 4; ++n) {
            int c = col0 + wc * 64 + n * 16 + cc;
#pragma unroll
            for (int j = 0; j < 4; ++j) {
                int r = r0 + j;
                if (r < M) C[(size_t)r * Nc + c] = acc[m][n][j];
            }
        }
    }
}

// ------------- fused layer-1 aggregate: pos + neg, relu + split -------------
// pos[n] = relu(dn*sum dinv[s]*hw[s] + dn^2*hw[n] + b)        -> pos hi/lo
// neg[n] = relu(dn*sum dinv[s]*hw[perm[s]] + dn^2*hw[perm[n]] + b) -> neg hi/lo
__global__ __launch_bounds__(256) void k_agg2(
        const float* __restrict__ hw, const int* __restrict__ rowptr,
        const int* __restrict__ csr, const int* __restrict__ perm,
        const float* __restrict__ dinv, const float* __restrict__ bias,
        unsigned short* __restrict__ pos_hi, unsigned short* __restrict__ pos_lo,
        unsigned short* __restrict__ neg_hi, unsigned short* __restrict__ neg_lo,
        int n) {
    int wid = (blockIdx.x * blockDim.x + threadIdx.x) >> 6;
    int lane = threadIdx.x & 63;
    if (wid >= n) return;
    float dn = dinv[wid];
    int beg = rowptr[wid], end = rowptr[wid + 1];
    int off = lane * 4;
    float ap[4] = {0.f, 0.f, 0.f, 0.f}, an[4] = {0.f, 0.f, 0.f, 0.f};
    for (int e = beg; e < end; ++e) {
        int s = csr[e];
        float ws = dinv[s];
        int sp = perm[s];
        float4 vp = *(const float4*)(hw + (size_t)s  * 256 + off);
        float4 vn = *(const float4*)(hw + (size_t)sp * 256 + off);
        ap[0] += ws * vp.x; ap[1] += ws * vp.y; ap[2] += ws * vp.z; ap[3] += ws * vp.w;
        an[0] += ws * vn.x; an[1] += ws * vn.y; an[2] += ws * vn.z; an[3] += ws * vn.w;
    }
    float sw = dn * dn;
    int pn = perm[wid];
    float4 mp = *(const float4*)(hw + (size_t)wid * 256 + off);
    float4 mn = *(const float4*)(hw + (size_t)pn  * 256 + off);
    float4 bv = *(const float4*)(bias + off);
    float rp[4], rn[4];
    rp[0] = fmaxf(dn * ap[0] + sw * mp.x + bv.x, 0.f);
    rp[1] = fmaxf(dn * ap[1] + sw * mp.y + bv.y, 0.f);
    rp[2] = fmaxf(dn * ap[2] + sw * mp.z + bv.z, 0.f);
    rp[3] = fmaxf(dn * ap[3] + sw * mp.w + bv.w, 0.f);
    rn[0] = fmaxf(dn * an[0] + sw * mn.x + bv.x, 0.f);
    rn[1] = fmaxf(dn * an[1] + sw * mn.y + bv.y, 0.f);
    rn[2] = fmaxf(dn * an[2] + sw * mn.z + bv.z, 0.f);
    rn[3] = fmaxf(dn * an[3] + sw * mn.w + bv.w, 0.f);
    u16x4 ph, pl, nh, nl;
#pragma unroll
    for (int j = 0; j < 4; ++j) {
        unsigned short hb = f2b(rp[j]);
        ph[j] = hb; pl[j] = f2b(rp[j] - b2f(hb));
        hb = f2b(rn[j]);
        nh[j] = hb; nl[j] = f2b(rn[j] - b2f(hb));
    }
    size_t o = (size_t)wid * 256 + off;
    *(u16x4*)(pos_hi + o) = ph;
    *(u16x4*)(pos_lo + o) = pl;
    *(u16x4*)(neg_hi + o) = nh;
    *(u16x4*)(neg_lo + o) = nl;
}

// ------------------- layer-2 aggregate (F=128, f32 out) ---------------------
__global__ __launch_bounds__(256) void k_agg128(
        const float* __restrict__ hw, const int* __restrict__ rowptr,
        const int* __restrict__ csr, const float* __restrict__ dinv,
        const float* __restrict__ bias, float* __restrict__ out, int n) {
    int wid = (blockIdx.x * blockDim.x + threadIdx.x) >> 6;
    int lane = threadIdx.x & 63;
    if (wid >= n) return;
    float dn = dinv[wid];
    int beg = rowptr[wid], end = rowptr[wid + 1];
    int off = lane * 2;
    float a0 = 0.f, a1 = 0.f;
    for (int e = beg; e < end; ++e) {
        int s = csr[e];
        float ws = dinv[s];
        float2 v = *(const float2*)(hw + (size_t)s * 128 + off);
        a0 += ws * v.x; a1 += ws * v.y;
    }
    float sw = dn * dn;
    float2 my = *(const float2*)(hw + (size_t)wid * 128 + off);
    float2 bv = *(const float2*)(bias + off);
    float2 r;
    r.x = dn * a0 + sw * my.x + bv.x;
    r.y = dn * a1 + sw * my.y + bv.y;
    *(float2*)(out + (size_t)wid * 128 + off) = r;
}

// ----------------------------- tail kernels ---------------------------------
__global__ void k_colsum(const float* __restrict__ H, float* __restrict__ colsum, int n) {
    int c = threadIdx.x & 127, half = threadIdx.x >> 7;
    float acc = 0.f;
    for (int r = blockIdx.x * 2 + half; r < n; r += gridDim.x * 2)
        acc += H[(size_t)r * 128 + c];
    __shared__ float sh[256];
    sh[threadIdx.x] = acc;
    __syncthreads();
    if (half == 0) atomicAdd(&colsum[c], sh[c] + sh[c + 128]);
}

__global__ void k_summary(const float* __restrict__ colsum, const float* __restrict__ Wb,
                          float* __restrict__ t, int n) {
    __shared__ float s_sh[128];
    int d = threadIdx.x;
    float m = colsum[d] / (float)n;
    s_sh[d] = 1.0f / (1.0f + expf(-m));
    __syncthreads();
    float acc = 0.f;
    for (int e = 0; e < 128; ++e) acc += Wb[d * 128 + e] * s_sh[e];
    t[d] = acc;
}

__global__ void k_disc(const float* __restrict__ H, const float* __restrict__ t,
                       const float* __restrict__ bb, float* __restrict__ out, int n) {
    int wid = (blockIdx.x * blockDim.x + threadIdx.x) >> 6;
    int lane = threadIdx.x & 63;
    if (wid >= n) return;
    const float* row = H + (size_t)wid * 128;
    float p = row[lane] * t[lane] + row[lane + 64] * t[lane + 64];
#pragma unroll
    for (int off = 32; off > 0; off >>= 1) p += __shfl_down(p, off);
    if (lane == 0) out[wid] = p + bb[0];
}

// ---------------------------------------------------------------------------
extern "C" void kernel_launch(void* const* d_in, const int* in_sizes, int n_in,
                              void* d_out, int out_size, void* d_ws, size_t ws_size,
                              hipStream_t stream) {
    const float* x    = (const float*)d_in[0];
    const int*   ei   = (const int*)d_in[1];
    const int*   perm = (const int*)d_in[2];
    const float* W1   = (const float*)d_in[3];
    const float* b1   = (const float*)d_in[4];
    const float* W2   = (const float*)d_in[5];
    const float* b2   = (const float*)d_in[6];
    const float* Wb   = (const float*)d_in[7];
    const float* bb   = (const float*)d_in[8];
    float* out = (float*)d_out;

    const int N   = in_sizes[2];
    const int E   = in_sizes[1] / 2;
    const int IN  = in_sizes[0] / N;   // 256
    const int HID = in_sizes[4];       // 256
    const int OUT = in_sizes[6];       // 128
    const int* src = ei;
    const int* dst = ei + E;

    char* p = (char*)d_ws;
    auto alloc = [&](size_t bytes) -> void* {
        void* r = (void*)p;
        p += (bytes + 255) & ~(size_t)255;
        return r;
    };
    int*   deg    = (int*)alloc((size_t)N * 4);
    int*   cursor = (int*)alloc((size_t)N * 4);
    float* colsum = (float*)alloc(128 * 4);
    size_t zlen   = (size_t)(p - (char*)deg);
    int*   rowptr = (int*)alloc((size_t)(N + 1) * 4);
    int*   bsum   = (int*)alloc(128 * 4);
    int*   boff   = (int*)alloc(128 * 4);
    int*   csr    = (int*)alloc((size_t)E * 4);
    float* dinv   = (float*)alloc((size_t)N * 4);
    float* tvec   = (float*)alloc(128 * 4);
    unsigned short* W1thi = (unsigned short*)alloc((size_t)IN * HID * 2);
    unsigned short* W1tlo = (unsigned short*)alloc((size_t)IN * HID * 2);
    unsigned short* W2thi = (unsigned short*)alloc((size_t)HID * OUT * 2);
    unsigned short* W2tlo = (unsigned short*)alloc((size_t)HID * OUT * 2);
    // P0: X planes, later reused for neg layer-1 split output
    unsigned short* Xhi = (unsigned short*)alloc((size_t)N * IN * 2);
    unsigned short* Xlo = (unsigned short*)alloc((size_t)N * IN * 2);
    // P1: GEMM1 f32 out, later G2pos / G2neg (each N*OUT*4 = half of P1)
    float* bufA = (float*)alloc((size_t)N * HID * 4);
    // P2: pos layer-1 split planes, later Hpos / Hneg
    unsigned short* Bphi = (unsigned short*)alloc((size_t)N * HID * 2);
    unsigned short* Bplo = (unsigned short*)alloc((size_t)N * HID * 2);

    unsigned short* Bnhi = Xhi;                 // aliases (X dead after GEMM1)
    unsigned short* Bnlo = Xlo;
    float* G2pos = bufA;                        // bufA dead after k_agg2
    float* G2neg = bufA + (size_t)N * OUT;
    float* Hpos  = (float*)Bphi;                // Bpos planes dead after GEMM2-pos
    float* Hneg  = (float*)Bplo;

    hipMemsetAsync(deg, 0, zlen, stream);

    int eb = (E + 255) / 256;
    int nb = (N + 255) / 256;
    int nscan = (N + 1023) / 1024;
    k_degree<<<eb, 256, 0, stream>>>(dst, deg, E);
    k_dinv<<<nb, 256, 0, stream>>>(deg, dinv, rowptr, N, E);
    k_scanA<<<nscan, 256, 0, stream>>>(deg, rowptr, bsum, N);
    k_scanB<<<1, 128, 0, stream>>>(bsum, boff, nscan);
    k_scanC<<<nscan, 256, 0, stream>>>(rowptr, boff, N);
    k_fill<<<eb, 256, 0, stream>>>(src, dst, rowptr, cursor, csr, E);

    // input + weight splits
    long n4 = (long)N * IN / 4;
    k_split<<<(int)((n4 + 255) / 256), 256, 0, stream>>>(x, Xhi, Xlo, n4);
    k_wsplitT<<<(IN * HID + 255) / 256, 256, 0, stream>>>(W1, W1thi, W1tlo, IN, HID);
    k_wsplitT<<<(HID * OUT + 255) / 256, 256, 0, stream>>>(W2, W2thi, W2tlo, HID, OUT);

    int mblk = (N + 127) / 128;
    int aggb = (N + 3) / 4;

    // layer 1: one GEMM serves pos and neg (permutation commutes)
    k_gemm_mfma<<<dim3(HID / 128, mblk), 256, 0, stream>>>(
        Xhi, Xlo, W1thi, W1tlo, bufA, N, IN, HID);
    k_agg2<<<aggb, 256, 0, stream>>>(bufA, rowptr, csr, perm, dinv, b1,
                                     Bphi, Bplo, Bnhi, Bnlo, N);

    // layer 2 pos
    k_gemm_mfma<<<dim3(OUT / 128, mblk), 256, 0, stream>>>(
        Bphi, Bplo, W2thi, W2tlo, G2pos, N, HID, OUT);
    k_agg128<<<aggb, 256, 0, stream>>>(G2pos, rowptr, csr, dinv, b2, Hpos, N);

    // layer 2 neg
    k_gemm_mfma<<<dim3(OUT / 128, mblk), 256, 0, stream>>>(
        Bnhi, Bnlo, W2thi, W2tlo, G2neg, N, HID, OUT);
    k_agg128<<<aggb, 256, 0, stream>>>(G2neg, rowptr, csr, dinv, b2, Hneg, N);

    // summary + discriminator
    k_colsum<<<256, 256, 0, stream>>>(Hpos, colsum, N);
    k_summary<<<1, 128, 0, stream>>>(colsum, Wb, tvec, N);
    int db = (int)(((size_t)N * 64 + 255) / 256);
    k_disc<<<db, 256, 0, stream>>>(Hpos, tvec, bb, out, N);
    k_disc<<<db, 256, 0, stream>>>(Hneg, tvec, bb, out + N, N);
}

// Round 3
// 1017.772 us; speedup vs baseline: 1.7229x; 1.4123x over previous
//
#include <hip/hip_runtime.h>

// ---------------------------------------------------------------------------
// DGI forward, round 3:
//  - aggregation gather tables (GEMM outputs) stored as bf16 -> halves the
//    dominant random-gather traffic; accumulation stays f32
//  - edge loop unrolled x2 for more loads in flight
//  - GEMMs remain split-bf16 MFMA (hi*hi + hi*lo + lo*hi), f32-accurate
// ---------------------------------------------------------------------------

typedef __attribute__((ext_vector_type(8))) short bh8;     // 8 bf16 (4 VGPR)
typedef __attribute__((ext_vector_type(4))) float f4;      // MFMA acc
typedef __attribute__((ext_vector_type(4))) unsigned short u16x4;

#define AS1 __attribute__((address_space(1)))
#define AS3 __attribute__((address_space(3)))

__device__ __forceinline__ unsigned short f2b(float f) {   // f32 -> bf16 RTNE
    unsigned int u = __float_as_uint(f);
    unsigned int r = (u + 0x7FFFu + ((u >> 16) & 1u)) >> 16;
    return (unsigned short)r;
}
__device__ __forceinline__ float b2f(unsigned short h) {
    return __uint_as_float(((unsigned int)h) << 16);
}

// ----------------------------- CSR build -----------------------------------
__global__ void k_degree(const int* __restrict__ dst, int* __restrict__ deg, int E) {
    int e = blockIdx.x * blockDim.x + threadIdx.x;
    if (e < E) atomicAdd(&deg[dst[e]], 1);
}

__global__ void k_dinv(const int* __restrict__ deg, float* __restrict__ dinv,
                       int* __restrict__ rowptr, int N, int E) {
    int n = blockIdx.x * blockDim.x + threadIdx.x;
    if (n < N) dinv[n] = 1.0f / sqrtf(1.0f + (float)deg[n]);
    if (n == 0) rowptr[N] = E;
}

__global__ void k_scanA(const int* __restrict__ in, int* __restrict__ out,
                        int* __restrict__ bsum, int n) {
    __shared__ int sh[256];
    int t = threadIdx.x;
    int base = blockIdx.x * 1024 + t * 4;
    int v[4];
#pragma unroll
    for (int j = 0; j < 4; ++j) v[j] = (base + j < n) ? in[base + j] : 0;
    int s = v[0] + v[1] + v[2] + v[3];
    sh[t] = s;
    __syncthreads();
    for (int off = 1; off < 256; off <<= 1) {
        int u = (t >= off) ? sh[t - off] : 0;
        __syncthreads();
        sh[t] += u;
        __syncthreads();
    }
    int excl = sh[t] - s;
    if (t == 255) bsum[blockIdx.x] = sh[255];
    int run = excl;
#pragma unroll
    for (int j = 0; j < 4; ++j) {
        if (base + j < n) out[base + j] = run;
        run += v[j];
    }
}

__global__ void k_scanB(const int* __restrict__ bsum, int* __restrict__ boff, int nb) {
    __shared__ int sh[128];
    int t = threadIdx.x;
    int v = (t < nb) ? bsum[t] : 0;
    sh[t] = v;
    __syncthreads();
    for (int off = 1; off < 128; off <<= 1) {
        int u = (t >= off) ? sh[t - off] : 0;
        __syncthreads();
        sh[t] += u;
        __syncthreads();
    }
    boff[t] = sh[t] - v;
}

__global__ void k_scanC(int* __restrict__ out, const int* __restrict__ boff, int n) {
    int t = threadIdx.x;
    int base = blockIdx.x * 1024 + t * 4;
    int add = boff[blockIdx.x];
#pragma unroll
    for (int j = 0; j < 4; ++j)
        if (base + j < n) out[base + j] += add;
}

__global__ void k_fill(const int* __restrict__ src, const int* __restrict__ dst,
                       const int* __restrict__ rowptr, int* __restrict__ cursor,
                       int* __restrict__ csr, int E) {
    int e = blockIdx.x * blockDim.x + threadIdx.x;
    if (e >= E) return;
    int d = dst[e];
    int p = rowptr[d] + atomicAdd(&cursor[d], 1);
    csr[p] = src[e];
}

// ------------------------- f32 -> bf16 hi/lo split --------------------------
__global__ void k_split(const float* __restrict__ in, unsigned short* __restrict__ hi,
                        unsigned short* __restrict__ lo, long n4) {
    long i = (long)blockIdx.x * blockDim.x + threadIdx.x;
    if (i >= n4) return;
    float4 v = ((const float4*)in)[i];
    float f[4] = {v.x, v.y, v.z, v.w};
    u16x4 h, l;
#pragma unroll
    for (int j = 0; j < 4; ++j) {
        unsigned short hb = f2b(f[j]);
        h[j] = hb;
        l[j] = f2b(f[j] - b2f(hb));
    }
    ((u16x4*)hi)[i] = h;
    ((u16x4*)lo)[i] = l;
}

// W [K][Nc] f32 -> Wt_hi/lo [Nc][K] bf16 (transpose + split)
__global__ void k_wsplitT(const float* __restrict__ W, unsigned short* __restrict__ thi,
                          unsigned short* __restrict__ tlo, int K, int Nc) {
    int t = blockIdx.x * blockDim.x + threadIdx.x;
    if (t >= K * Nc) return;
    int k = t / Nc, n = t % Nc;
    float f = W[t];
    unsigned short hb = f2b(f);
    thi[n * K + k] = hb;
    tlo[n * K + k] = f2b(f - b2f(hb));
}

// --------------- split-bf16 MFMA GEMM (C = A@B, bf16 output) ----------------
// A planes [M][K] bf16 hi/lo, B planes [Nc][K] bf16 hi/lo (pre-transposed).
// BM=BN=128, BK=32, 256 threads (4 waves, 2x2 of 64x64 wave tiles).
__global__ __launch_bounds__(256, 2) void k_gemm_mfma(
        const unsigned short* __restrict__ Ahi, const unsigned short* __restrict__ Alo,
        const unsigned short* __restrict__ Bhi, const unsigned short* __restrict__ Blo,
        unsigned short* __restrict__ C, int M, int K, int Nc) {
    __shared__ short lds[4][128 * 32];          // planes: Ahi, Alo, Bhi, Blo (32 KB)
    const int tid  = threadIdx.x;
    const int lane = tid & 63;
    const int w    = tid >> 6;                  // wave 0..3
    const int wr   = w >> 1, wc = w & 1;
    const int row0 = blockIdx.y * 128;
    const int col0 = blockIdx.x * 128;

    const unsigned short* sp = (w == 0) ? Ahi : (w == 1) ? Alo : (w == 2) ? Bhi : Blo;
    const int  base0 = (w < 2) ? row0 : col0;
    const int  lim   = (w < 2) ? (M - 1) : (Nc - 1);
    const int  rsub  = lane >> 2;               // 0..15 row within slab
    const int  clin  = lane & 3;                // 16B chunk within 64B row

    f4 acc[4][4] = {};

    for (int k0 = 0; k0 < K; k0 += 32) {
        __syncthreads();
#pragma unroll
        for (int s = 0; s < 8; ++s) {
            int r = s * 16 + rsub;
            int g = base0 + r;
            if (g > lim) g = lim;
            const unsigned short* src = sp + (size_t)g * K + k0 + clin * 8;
            __builtin_amdgcn_global_load_lds((const AS1 void*)src,
                                             (AS3 void*)&lds[w][s * 512], 16, 0, 0);
        }
        __syncthreads();

        bh8 ah[4], al[4], bh_[4], bl[4];
        const int fr = lane & 15;
        const int fc = (lane >> 4) * 8;
#pragma unroll
        for (int m = 0; m < 4; ++m) {
            int off = (wr * 64 + m * 16 + fr) * 32 + fc;
            ah[m] = *(const bh8*)&lds[0][off];
            al[m] = *(const bh8*)&lds[1][off];
        }
#pragma unroll
        for (int n = 0; n < 4; ++n) {
            int off = (wc * 64 + n * 16 + fr) * 32 + fc;
            bh_[n] = *(const bh8*)&lds[2][off];
            bl[n]  = *(const bh8*)&lds[3][off];
        }
#pragma unroll
        for (int m = 0; m < 4; ++m)
#pragma unroll
            for (int n = 0; n < 4; ++n)
                acc[m][n] = __builtin_amdgcn_mfma_f32_16x16x32_bf16(ah[m], bh_[n], acc[m][n], 0, 0, 0);
#pragma unroll
        for (int m = 0; m < 4; ++m)
#pragma unroll
            for (int n = 0; n < 4; ++n)
                acc[m][n] = __builtin_amdgcn_mfma_f32_16x16x32_bf16(ah[m], bl[n], acc[m][n], 0, 0, 0);
#pragma unroll
        for (int m = 0; m < 4; ++m)
#pragma unroll
            for (int n = 0; n < 4; ++n)
                acc[m][n] = __builtin_amdgcn_mfma_f32_16x16x32_bf16(al[m], bh_[n], acc[m][n], 0, 0, 0);
    }

    // C/D layout: col=lane&15, row=(lane>>4)*4+reg
    const int cr = (lane >> 4) * 4;
    const int cc = lane & 15;
#pragma unroll
    for (int m = 0; m < 4; ++m) {
        int r0 = row0 + wr * 64 + m * 16 + cr;
#pragma unroll
        for (int n = 0; n < 4; ++n) {
            int c = col0 + wc * 64 + n * 16 + cc;
#pragma unroll
            for (int j = 0; j < 4; ++j) {
                int r = r0 + j;
                if (r < M) C[(size_t)r * Nc + c] = f2b(acc[m][n][j]);
            }
        }
    }
}

// ------------- fused layer-1 aggregate: pos + neg, relu + split -------------
// hw is bf16 [N][256]; accumulate f32; outputs hi/lo bf16 planes for GEMM2.
__global__ __launch_bounds__(256) void k_agg2(
        const unsigned short* __restrict__ hw, const int* __restrict__ rowptr,
        const int* __restrict__ csr, const int* __restrict__ perm,
        const float* __restrict__ dinv, const float* __restrict__ bias,
        unsigned short* __restrict__ pos_hi, unsigned short* __restrict__ pos_lo,
        unsigned short* __restrict__ neg_hi, unsigned short* __restrict__ neg_lo,
        int n) {
    int wid = (blockIdx.x * blockDim.x + threadIdx.x) >> 6;
    int lane = threadIdx.x & 63;
    if (wid >= n) return;
    float dn = dinv[wid];
    int beg = rowptr[wid], end = rowptr[wid + 1];
    int off = lane * 4;
    float ap[4] = {0.f, 0.f, 0.f, 0.f}, an[4] = {0.f, 0.f, 0.f, 0.f};
    int e = beg;
    for (; e + 1 < end; e += 2) {
        int s0 = csr[e], s1 = csr[e + 1];
        float w0 = dinv[s0], w1 = dinv[s1];
        int p0 = perm[s0], p1 = perm[s1];
        u16x4 vp0 = *(const u16x4*)(hw + (size_t)s0 * 256 + off);
        u16x4 vn0 = *(const u16x4*)(hw + (size_t)p0 * 256 + off);
        u16x4 vp1 = *(const u16x4*)(hw + (size_t)s1 * 256 + off);
        u16x4 vn1 = *(const u16x4*)(hw + (size_t)p1 * 256 + off);
#pragma unroll
        for (int j = 0; j < 4; ++j) {
            ap[j] += w0 * b2f(vp0[j]) + w1 * b2f(vp1[j]);
            an[j] += w0 * b2f(vn0[j]) + w1 * b2f(vn1[j]);
        }
    }
    for (; e < end; ++e) {
        int s0 = csr[e];
        float w0 = dinv[s0];
        int p0 = perm[s0];
        u16x4 vp0 = *(const u16x4*)(hw + (size_t)s0 * 256 + off);
        u16x4 vn0 = *(const u16x4*)(hw + (size_t)p0 * 256 + off);
#pragma unroll
        for (int j = 0; j < 4; ++j) {
            ap[j] += w0 * b2f(vp0[j]);
            an[j] += w0 * b2f(vn0[j]);
        }
    }
    float sw = dn * dn;
    int pn = perm[wid];
    u16x4 mp = *(const u16x4*)(hw + (size_t)wid * 256 + off);
    u16x4 mn = *(const u16x4*)(hw + (size_t)pn  * 256 + off);
    float4 bv = *(const float4*)(bias + off);
    float bb4[4] = {bv.x, bv.y, bv.z, bv.w};
    u16x4 ph, pl, nh, nl;
#pragma unroll
    for (int j = 0; j < 4; ++j) {
        float rp = fmaxf(dn * ap[j] + sw * b2f(mp[j]) + bb4[j], 0.f);
        float rn = fmaxf(dn * an[j] + sw * b2f(mn[j]) + bb4[j], 0.f);
        unsigned short hb = f2b(rp);
        ph[j] = hb; pl[j] = f2b(rp - b2f(hb));
        hb = f2b(rn);
        nh[j] = hb; nl[j] = f2b(rn - b2f(hb));
    }
    size_t o = (size_t)wid * 256 + off;
    *(u16x4*)(pos_hi + o) = ph;
    *(u16x4*)(pos_lo + o) = pl;
    *(u16x4*)(neg_hi + o) = nh;
    *(u16x4*)(neg_lo + o) = nl;
}

// ------------------- layer-2 aggregate (bf16 in, f32 out) -------------------
__global__ __launch_bounds__(256) void k_agg128(
        const unsigned short* __restrict__ hw, const int* __restrict__ rowptr,
        const int* __restrict__ csr, const float* __restrict__ dinv,
        const float* __restrict__ bias, float* __restrict__ out, int n) {
    int wid = (blockIdx.x * blockDim.x + threadIdx.x) >> 6;
    int lane = threadIdx.x & 63;
    if (wid >= n) return;
    float dn = dinv[wid];
    int beg = rowptr[wid], end = rowptr[wid + 1];
    int off = lane * 2;
    float a0 = 0.f, a1 = 0.f;
    int e = beg;
    for (; e + 1 < end; e += 2) {
        int s0 = csr[e], s1 = csr[e + 1];
        float w0 = dinv[s0], w1 = dinv[s1];
        ushort2 v0 = *(const ushort2*)(hw + (size_t)s0 * 128 + off);
        ushort2 v1 = *(const ushort2*)(hw + (size_t)s1 * 128 + off);
        a0 += w0 * b2f(v0.x) + w1 * b2f(v1.x);
        a1 += w0 * b2f(v0.y) + w1 * b2f(v1.y);
    }
    for (; e < end; ++e) {
        int s0 = csr[e];
        float w0 = dinv[s0];
        ushort2 v0 = *(const ushort2*)(hw + (size_t)s0 * 128 + off);
        a0 += w0 * b2f(v0.x);
        a1 += w0 * b2f(v0.y);
    }
    float sw = dn * dn;
    ushort2 my = *(const ushort2*)(hw + (size_t)wid * 128 + off);
    float2 bv = *(const float2*)(bias + off);
    float2 r;
    r.x = dn * a0 + sw * b2f(my.x) + bv.x;
    r.y = dn * a1 + sw * b2f(my.y) + bv.y;
    *(float2*)(out + (size_t)wid * 128 + off) = r;
}

// ----------------------------- tail kernels ---------------------------------
__global__ void k_colsum(const float* __restrict__ H, float* __restrict__ colsum, int n) {
    int c = threadIdx.x & 127, half = threadIdx.x >> 7;
    float acc = 0.f;
    for (int r = blockIdx.x * 2 + half; r < n; r += gridDim.x * 2)
        acc += H[(size_t)r * 128 + c];
    __shared__ float sh[256];
    sh[threadIdx.x] = acc;
    __syncthreads();
    if (half == 0) atomicAdd(&colsum[c], sh[c] + sh[c + 128]);
}

__global__ void k_summary(const float* __restrict__ colsum, const float* __restrict__ Wb,
                          float* __restrict__ t, int n) {
    __shared__ float s_sh[128];
    int d = threadIdx.x;
    float m = colsum[d] / (float)n;
    s_sh[d] = 1.0f / (1.0f + expf(-m));
    __syncthreads();
    float acc = 0.f;
    for (int e = 0; e < 128; ++e) acc += Wb[d * 128 + e] * s_sh[e];
    t[d] = acc;
}

__global__ void k_disc(const float* __restrict__ H, const float* __restrict__ t,
                       const float* __restrict__ bb, float* __restrict__ out, int n) {
    int wid = (blockIdx.x * blockDim.x + threadIdx.x) >> 6;
    int lane = threadIdx.x & 63;
    if (wid >= n) return;
    const float* row = H + (size_t)wid * 128;
    float p = row[lane] * t[lane] + row[lane + 64] * t[lane + 64];
#pragma unroll
    for (int off = 32; off > 0; off >>= 1) p += __shfl_down(p, off);
    if (lane == 0) out[wid] = p + bb[0];
}

// ---------------------------------------------------------------------------
extern "C" void kernel_launch(void* const* d_in, const int* in_sizes, int n_in,
                              void* d_out, int out_size, void* d_ws, size_t ws_size,
                              hipStream_t stream) {
    const float* x    = (const float*)d_in[0];
    const int*   ei   = (const int*)d_in[1];
    const int*   perm = (const int*)d_in[2];
    const float* W1   = (const float*)d_in[3];
    const float* b1   = (const float*)d_in[4];
    const float* W2   = (const float*)d_in[5];
    const float* b2   = (const float*)d_in[6];
    const float* Wb   = (const float*)d_in[7];
    const float* bb   = (const float*)d_in[8];
    float* out = (float*)d_out;

    const int N   = in_sizes[2];
    const int E   = in_sizes[1] / 2;
    const int IN  = in_sizes[0] / N;   // 256
    const int HID = in_sizes[4];       // 256
    const int OUT = in_sizes[6];       // 128
    const int* src = ei;
    const int* dst = ei + E;

    char* p = (char*)d_ws;
    auto alloc = [&](size_t bytes) -> void* {
        void* r = (void*)p;
        p += (bytes + 255) & ~(size_t)255;
        return r;
    };
    int*   deg    = (int*)alloc((size_t)N * 4);
    int*   cursor = (int*)alloc((size_t)N * 4);
    float* colsum = (float*)alloc(128 * 4);
    size_t zlen   = (size_t)(p - (char*)deg);
    int*   rowptr = (int*)alloc((size_t)(N + 1) * 4);
    int*   bsum   = (int*)alloc(128 * 4);
    int*   boff   = (int*)alloc(128 * 4);
    int*   csr    = (int*)alloc((size_t)E * 4);
    float* dinv   = (float*)alloc((size_t)N * 4);
    float* tvec   = (float*)alloc(128 * 4);
    unsigned short* W1thi = (unsigned short*)alloc((size_t)IN * HID * 2);
    unsigned short* W1tlo = (unsigned short*)alloc((size_t)IN * HID * 2);
    unsigned short* W2thi = (unsigned short*)alloc((size_t)HID * OUT * 2);
    unsigned short* W2tlo = (unsigned short*)alloc((size_t)HID * OUT * 2);
    // P0: X split planes; reused as neg layer-1 split planes after GEMM1
    unsigned short* Xhi = (unsigned short*)alloc((size_t)N * IN * 2);
    unsigned short* Xlo = (unsigned short*)alloc((size_t)N * IN * 2);
    // P1: G1 (GEMM1 bf16 out); later holds G2pos + G2neg (each N*OUT bf16)
    unsigned short* G1 = (unsigned short*)alloc((size_t)N * HID * 2);
    // P2: pos layer-1 split planes; later Hpos / Hneg (f32, N*OUT each)
    unsigned short* Bphi = (unsigned short*)alloc((size_t)N * HID * 2);
    unsigned short* Bplo = (unsigned short*)alloc((size_t)N * HID * 2);

    unsigned short* Bnhi = Xhi;                  // X dead after GEMM1
    unsigned short* Bnlo = Xlo;
    unsigned short* G2pos = G1;                  // G1 dead after k_agg2
    unsigned short* G2neg = G1 + (size_t)N * OUT;
    float* Hpos = (float*)Bphi;                  // Bpos dead after GEMM2-pos
    float* Hneg = (float*)Bplo;                  // Bplo dead after GEMM2-neg... (see order)

    hipMemsetAsync(deg, 0, zlen, stream);

    int eb = (E + 255) / 256;
    int nb = (N + 255) / 256;
    int nscan = (N + 1023) / 1024;
    k_degree<<<eb, 256, 0, stream>>>(dst, deg, E);
    k_dinv<<<nb, 256, 0, stream>>>(deg, dinv, rowptr, N, E);
    k_scanA<<<nscan, 256, 0, stream>>>(deg, rowptr, bsum, N);
    k_scanB<<<1, 128, 0, stream>>>(bsum, boff, nscan);
    k_scanC<<<nscan, 256, 0, stream>>>(rowptr, boff, N);
    k_fill<<<eb, 256, 0, stream>>>(src, dst, rowptr, cursor, csr, E);

    long n4 = (long)N * IN / 4;
    k_split<<<(int)((n4 + 255) / 256), 256, 0, stream>>>(x, Xhi, Xlo, n4);
    k_wsplitT<<<(IN * HID + 255) / 256, 256, 0, stream>>>(W1, W1thi, W1tlo, IN, HID);
    k_wsplitT<<<(HID * OUT + 255) / 256, 256, 0, stream>>>(W2, W2thi, W2tlo, HID, OUT);

    int mblk = (N + 127) / 128;
    int aggb = (N + 3) / 4;

    // layer 1: one GEMM serves pos and neg (row permutation commutes)
    k_gemm_mfma<<<dim3(HID / 128, mblk), 256, 0, stream>>>(
        Xhi, Xlo, W1thi, W1tlo, G1, N, IN, HID);
    k_agg2<<<aggb, 256, 0, stream>>>(G1, rowptr, csr, perm, dinv, b1,
                                     Bphi, Bplo, Bnhi, Bnlo, N);

    // layer 2 pos: GEMM2 -> G2pos (bf16), aggregate -> Hpos (f32, overwrites Bphi)
    k_gemm_mfma<<<dim3(OUT / 128, mblk), 256, 0, stream>>>(
        Bphi, Bplo, W2thi, W2tlo, G2pos, N, HID, OUT);
    k_agg128<<<aggb, 256, 0, stream>>>(G2pos, rowptr, csr, dinv, b2, Hpos, N);

    // layer 2 neg
    k_gemm_mfma<<<dim3(OUT / 128, mblk), 256, 0, stream>>>(
        Bnhi, Bnlo, W2thi, W2tlo, G2neg, N, HID, OUT);
    k_agg128<<<aggb, 256, 0, stream>>>(G2neg, rowptr, csr, dinv, b2, Hneg, N);

    // summary + discriminator
    k_colsum<<<256, 256, 0, stream>>>(Hpos, colsum, N);
    k_summary<<<1, 128, 0, stream>>>(colsum, Wb, tvec, N);
    int db = (int)(((size_t)N * 64 + 255) / 256);
    k_disc<<<db, 256, 0, stream>>>(Hpos, tvec, bb, out, N);
    k_disc<<<db, 256, 0, stream>>>(Hneg, tvec, bb, out + N, N);
}

// Round 5
// 989.208 us; speedup vs baseline: 1.7727x; 1.0289x over previous
//
#include <hip/hip_runtime.h>

// ---------------------------------------------------------------------------
// DGI forward, round 5 (round-4 fix: NT store needs ext_vector float type):
//  - pcsr[e] = perm[src[e]] precomputed in k_fill -> kills the dependent
//    perm[csr[e]] pointer chase in the hot gather loop
//  - agg2 edge loop unrolled x4 (8 independent gathers in flight)
//  - nontemporal stores for aggregate outputs (protect gather tables in L3)
//  - layer-2: single GEMM launch (grid.z = pos/neg) into interleaved G2
//    [N][256] (cols 0..127 pos | 128..255 neg); merged agg128; merged disc
// ---------------------------------------------------------------------------

typedef __attribute__((ext_vector_type(8))) short bh8;     // 8 bf16 (4 VGPR)
typedef __attribute__((ext_vector_type(4))) float f4;      // MFMA acc / NT f32x4
typedef __attribute__((ext_vector_type(4))) unsigned short u16x4;

#define AS1 __attribute__((address_space(1)))
#define AS3 __attribute__((address_space(3)))

__device__ __forceinline__ unsigned short f2b(float f) {   // f32 -> bf16 RTNE
    unsigned int u = __float_as_uint(f);
    unsigned int r = (u + 0x7FFFu + ((u >> 16) & 1u)) >> 16;
    return (unsigned short)r;
}
__device__ __forceinline__ float b2f(unsigned short h) {
    return __uint_as_float(((unsigned int)h) << 16);
}

// ----------------------------- CSR build -----------------------------------
__global__ void k_degree(const int* __restrict__ dst, int* __restrict__ deg, int E) {
    int e = blockIdx.x * blockDim.x + threadIdx.x;
    if (e < E) atomicAdd(&deg[dst[e]], 1);
}

__global__ void k_dinv(const int* __restrict__ deg, float* __restrict__ dinv,
                       int* __restrict__ rowptr, int N, int E) {
    int n = blockIdx.x * blockDim.x + threadIdx.x;
    if (n < N) dinv[n] = 1.0f / sqrtf(1.0f + (float)deg[n]);
    if (n == 0) rowptr[N] = E;
}

__global__ void k_scanA(const int* __restrict__ in, int* __restrict__ out,
                        int* __restrict__ bsum, int n) {
    __shared__ int sh[256];
    int t = threadIdx.x;
    int base = blockIdx.x * 1024 + t * 4;
    int v[4];
#pragma unroll
    for (int j = 0; j < 4; ++j) v[j] = (base + j < n) ? in[base + j] : 0;
    int s = v[0] + v[1] + v[2] + v[3];
    sh[t] = s;
    __syncthreads();
    for (int off = 1; off < 256; off <<= 1) {
        int u = (t >= off) ? sh[t - off] : 0;
        __syncthreads();
        sh[t] += u;
        __syncthreads();
    }
    int excl = sh[t] - s;
    if (t == 255) bsum[blockIdx.x] = sh[255];
    int run = excl;
#pragma unroll
    for (int j = 0; j < 4; ++j) {
        if (base + j < n) out[base + j] = run;
        run += v[j];
    }
}

__global__ void k_scanB(const int* __restrict__ bsum, int* __restrict__ boff, int nb) {
    __shared__ int sh[128];
    int t = threadIdx.x;
    int v = (t < nb) ? bsum[t] : 0;
    sh[t] = v;
    __syncthreads();
    for (int off = 1; off < 128; off <<= 1) {
        int u = (t >= off) ? sh[t - off] : 0;
        __syncthreads();
        sh[t] += u;
        __syncthreads();
    }
    boff[t] = sh[t] - v;
}

__global__ void k_scanC(int* __restrict__ out, const int* __restrict__ boff, int n) {
    int t = threadIdx.x;
    int base = blockIdx.x * 1024 + t * 4;
    int add = boff[blockIdx.x];
#pragma unroll
    for (int j = 0; j < 4; ++j)
        if (base + j < n) out[base + j] += add;
}

// fill csr (src ids) and pcsr (perm[src] ids) in one pass
__global__ void k_fill(const int* __restrict__ src, const int* __restrict__ dst,
                       const int* __restrict__ perm, const int* __restrict__ rowptr,
                       int* __restrict__ cursor, int* __restrict__ csr,
                       int* __restrict__ pcsr, int E) {
    int e = blockIdx.x * blockDim.x + threadIdx.x;
    if (e >= E) return;
    int d = dst[e];
    int s = src[e];
    int p = rowptr[d] + atomicAdd(&cursor[d], 1);
    csr[p] = s;
    pcsr[p] = perm[s];
}

// ------------------------- f32 -> bf16 hi/lo split --------------------------
__global__ void k_split(const float* __restrict__ in, unsigned short* __restrict__ hi,
                        unsigned short* __restrict__ lo, long n4) {
    long i = (long)blockIdx.x * blockDim.x + threadIdx.x;
    if (i >= n4) return;
    float4 v = ((const float4*)in)[i];
    float f[4] = {v.x, v.y, v.z, v.w};
    u16x4 h, l;
#pragma unroll
    for (int j = 0; j < 4; ++j) {
        unsigned short hb = f2b(f[j]);
        h[j] = hb;
        l[j] = f2b(f[j] - b2f(hb));
    }
    ((u16x4*)hi)[i] = h;
    ((u16x4*)lo)[i] = l;
}

// W [K][Nc] f32 -> Wt_hi/lo [Nc][K] bf16 (transpose + split)
__global__ void k_wsplitT(const float* __restrict__ W, unsigned short* __restrict__ thi,
                          unsigned short* __restrict__ tlo, int K, int Nc) {
    int t = blockIdx.x * blockDim.x + threadIdx.x;
    if (t >= K * Nc) return;
    int k = t / Nc, n = t % Nc;
    float f = W[t];
    unsigned short hb = f2b(f);
    thi[n * K + k] = hb;
    tlo[n * K + k] = f2b(f - b2f(hb));
}

// --------------- split-bf16 MFMA GEMM (C = A@B, bf16 output) ----------------
// A planes [M][K] bf16 hi/lo (blockIdx.z picks set 0/1), B planes [NcB][K].
// BM=BN=128, BK=32, 256 threads (4 waves, 2x2 of 64x64 wave tiles).
// C element (r,c) written to C[r*ldC + blockIdx.x*128 + blockIdx.z*colz + c].
__global__ __launch_bounds__(256, 2) void k_gemm_mfma(
        const unsigned short* __restrict__ Ahi0, const unsigned short* __restrict__ Alo0,
        const unsigned short* __restrict__ Ahi1, const unsigned short* __restrict__ Alo1,
        const unsigned short* __restrict__ Bhi, const unsigned short* __restrict__ Blo,
        unsigned short* __restrict__ C, int M, int K, int NcB, int ldC, int colz) {
    __shared__ short lds[4][128 * 32];          // planes: Ahi, Alo, Bhi, Blo (32 KB)
    const int tid  = threadIdx.x;
    const int lane = tid & 63;
    const int w    = tid >> 6;                  // wave 0..3
    const int wr   = w >> 1, wc = w & 1;
    const int row0 = blockIdx.y * 128;
    const int bcol = blockIdx.x * 128;          // col within B table
    const unsigned short* Ahi = blockIdx.z ? Ahi1 : Ahi0;
    const unsigned short* Alo = blockIdx.z ? Alo1 : Alo0;

    const unsigned short* sp = (w == 0) ? Ahi : (w == 1) ? Alo : (w == 2) ? Bhi : Blo;
    const int  base0 = (w < 2) ? row0 : bcol;
    const int  lim   = (w < 2) ? (M - 1) : (NcB - 1);
    const int  rsub  = lane >> 2;               // 0..15 row within slab
    const int  clin  = lane & 3;                // 16B chunk within 64B row

    f4 acc[4][4] = {};

    for (int k0 = 0; k0 < K; k0 += 32) {
        __syncthreads();
#pragma unroll
        for (int s = 0; s < 8; ++s) {
            int r = s * 16 + rsub;
            int g = base0 + r;
            if (g > lim) g = lim;
            const unsigned short* srcp = sp + (size_t)g * K + k0 + clin * 8;
            __builtin_amdgcn_global_load_lds((const AS1 void*)srcp,
                                             (AS3 void*)&lds[w][s * 512], 16, 0, 0);
        }
        __syncthreads();

        bh8 ah[4], al[4], bh_[4], bl[4];
        const int fr = lane & 15;
        const int fc = (lane >> 4) * 8;
#pragma unroll
        for (int m = 0; m < 4; ++m) {
            int off = (wr * 64 + m * 16 + fr) * 32 + fc;
            ah[m] = *(const bh8*)&lds[0][off];
            al[m] = *(const bh8*)&lds[1][off];
        }
#pragma unroll
        for (int n = 0; n < 4; ++n) {
            int off = (wc * 64 + n * 16 + fr) * 32 + fc;
            bh_[n] = *(const bh8*)&lds[2][off];
            bl[n]  = *(const bh8*)&lds[3][off];
        }
#pragma unroll
        for (int m = 0; m < 4; ++m)
#pragma unroll
            for (int n = 0; n < 4; ++n)
                acc[m][n] = __builtin_amdgcn_mfma_f32_16x16x32_bf16(ah[m], bh_[n], acc[m][n], 0, 0, 0);
#pragma unroll
        for (int m = 0; m < 4; ++m)
#pragma unroll
            for (int n = 0; n < 4; ++n)
                acc[m][n] = __builtin_amdgcn_mfma_f32_16x16x32_bf16(ah[m], bl[n], acc[m][n], 0, 0, 0);
#pragma unroll
        for (int m = 0; m < 4; ++m)
#pragma unroll
            for (int n = 0; n < 4; ++n)
                acc[m][n] = __builtin_amdgcn_mfma_f32_16x16x32_bf16(al[m], bh_[n], acc[m][n], 0, 0, 0);
    }

    // C/D layout: col=lane&15, row=(lane>>4)*4+reg
    const int cr = (lane >> 4) * 4;
    const int cc = lane & 15;
    const int col0 = bcol + blockIdx.z * colz;
#pragma unroll
    for (int m = 0; m < 4; ++m) {
        int r0 = row0 + wr * 64 + m * 16 + cr;
#pragma unroll
        for (int n = 0; n < 4; ++n) {
            int c = col0 + wc * 64 + n * 16 + cc;
#pragma unroll
            for (int j = 0; j < 4; ++j) {
                int r = r0 + j;
                if (r < M) C[(size_t)r * ldC + c] = f2b(acc[m][n][j]);
            }
        }
    }
}

// ------------- fused layer-1 aggregate: pos + neg, relu + split -------------
// hw bf16 [N][256]; flat csr/pcsr index streams; f32 accum; NT-store planes.
__global__ __launch_bounds__(256) void k_agg2(
        const unsigned short* __restrict__ hw, const int* __restrict__ rowptr,
        const int* __restrict__ csr, const int* __restrict__ pcsr,
        const int* __restrict__ perm, const float* __restrict__ dinv,
        const float* __restrict__ bias,
        unsigned short* __restrict__ pos_hi, unsigned short* __restrict__ pos_lo,
        unsigned short* __restrict__ neg_hi, unsigned short* __restrict__ neg_lo,
        int n) {
    int wid = (blockIdx.x * blockDim.x + threadIdx.x) >> 6;
    int lane = threadIdx.x & 63;
    if (wid >= n) return;
    float dn = dinv[wid];
    int beg = rowptr[wid], end = rowptr[wid + 1];
    int off = lane * 4;
    float ap[4] = {0.f, 0.f, 0.f, 0.f}, an[4] = {0.f, 0.f, 0.f, 0.f};
    int e = beg;
    for (; e + 3 < end; e += 4) {
        int s0 = csr[e],     s1 = csr[e + 1], s2 = csr[e + 2], s3 = csr[e + 3];
        int p0 = pcsr[e],    p1 = pcsr[e + 1], p2 = pcsr[e + 2], p3 = pcsr[e + 3];
        float w0 = dinv[s0], w1 = dinv[s1],   w2 = dinv[s2],   w3 = dinv[s3];
        u16x4 vp0 = *(const u16x4*)(hw + (size_t)s0 * 256 + off);
        u16x4 vp1 = *(const u16x4*)(hw + (size_t)s1 * 256 + off);
        u16x4 vp2 = *(const u16x4*)(hw + (size_t)s2 * 256 + off);
        u16x4 vp3 = *(const u16x4*)(hw + (size_t)s3 * 256 + off);
        u16x4 vn0 = *(const u16x4*)(hw + (size_t)p0 * 256 + off);
        u16x4 vn1 = *(const u16x4*)(hw + (size_t)p1 * 256 + off);
        u16x4 vn2 = *(const u16x4*)(hw + (size_t)p2 * 256 + off);
        u16x4 vn3 = *(const u16x4*)(hw + (size_t)p3 * 256 + off);
#pragma unroll
        for (int j = 0; j < 4; ++j) {
            ap[j] += (w0 * b2f(vp0[j]) + w1 * b2f(vp1[j]))
                   + (w2 * b2f(vp2[j]) + w3 * b2f(vp3[j]));
            an[j] += (w0 * b2f(vn0[j]) + w1 * b2f(vn1[j]))
                   + (w2 * b2f(vn2[j]) + w3 * b2f(vn3[j]));
        }
    }
    for (; e < end; ++e) {
        int s0 = csr[e];
        int p0 = pcsr[e];
        float w0 = dinv[s0];
        u16x4 vp0 = *(const u16x4*)(hw + (size_t)s0 * 256 + off);
        u16x4 vn0 = *(const u16x4*)(hw + (size_t)p0 * 256 + off);
#pragma unroll
        for (int j = 0; j < 4; ++j) {
            ap[j] += w0 * b2f(vp0[j]);
            an[j] += w0 * b2f(vn0[j]);
        }
    }
    float sw = dn * dn;
    int pn = perm[wid];
    u16x4 mp = *(const u16x4*)(hw + (size_t)wid * 256 + off);
    u16x4 mn = *(const u16x4*)(hw + (size_t)pn  * 256 + off);
    float4 bv = *(const float4*)(bias + off);
    float bb4[4] = {bv.x, bv.y, bv.z, bv.w};
    u16x4 ph, pl, nh, nl;
#pragma unroll
    for (int j = 0; j < 4; ++j) {
        float rp = fmaxf(dn * ap[j] + sw * b2f(mp[j]) + bb4[j], 0.f);
        float rn = fmaxf(dn * an[j] + sw * b2f(mn[j]) + bb4[j], 0.f);
        unsigned short hb = f2b(rp);
        ph[j] = hb; pl[j] = f2b(rp - b2f(hb));
        hb = f2b(rn);
        nh[j] = hb; nl[j] = f2b(rn - b2f(hb));
    }
    size_t o = (size_t)wid * 256 + off;
    __builtin_nontemporal_store(ph, (u16x4*)(pos_hi + o));
    __builtin_nontemporal_store(pl, (u16x4*)(pos_lo + o));
    __builtin_nontemporal_store(nh, (u16x4*)(neg_hi + o));
    __builtin_nontemporal_store(nl, (u16x4*)(neg_lo + o));
}

// -------- merged layer-2 aggregate: G2 [N][256] = [pos(128) | neg(128)] -----
// lanes 0..31 accumulate pos features, lanes 32..63 neg features.
__global__ __launch_bounds__(256) void k_agg128m(
        const unsigned short* __restrict__ G2, const int* __restrict__ rowptr,
        const int* __restrict__ csr, const float* __restrict__ dinv,
        const float* __restrict__ bias, float* __restrict__ Hpos,
        float* __restrict__ Hneg, int n) {
    int wid = (blockIdx.x * blockDim.x + threadIdx.x) >> 6;
    int lane = threadIdx.x & 63;
    if (wid >= n) return;
    float dn = dinv[wid];
    int beg = rowptr[wid], end = rowptr[wid + 1];
    int off = lane * 4;                         // 0..252 across pos|neg halves
    float a[4] = {0.f, 0.f, 0.f, 0.f};
    int e = beg;
    for (; e + 3 < end; e += 4) {
        int s0 = csr[e], s1 = csr[e + 1], s2 = csr[e + 2], s3 = csr[e + 3];
        float w0 = dinv[s0], w1 = dinv[s1], w2 = dinv[s2], w3 = dinv[s3];
        u16x4 v0 = *(const u16x4*)(G2 + (size_t)s0 * 256 + off);
        u16x4 v1 = *(const u16x4*)(G2 + (size_t)s1 * 256 + off);
        u16x4 v2 = *(const u16x4*)(G2 + (size_t)s2 * 256 + off);
        u16x4 v3 = *(const u16x4*)(G2 + (size_t)s3 * 256 + off);
#pragma unroll
        for (int j = 0; j < 4; ++j)
            a[j] += (w0 * b2f(v0[j]) + w1 * b2f(v1[j]))
                  + (w2 * b2f(v2[j]) + w3 * b2f(v3[j]));
    }
    for (; e < end; ++e) {
        int s0 = csr[e];
        float w0 = dinv[s0];
        u16x4 v0 = *(const u16x4*)(G2 + (size_t)s0 * 256 + off);
#pragma unroll
        for (int j = 0; j < 4; ++j) a[j] += w0 * b2f(v0[j]);
    }
    float sw = dn * dn;
    u16x4 mv = *(const u16x4*)(G2 + (size_t)wid * 256 + off);
    float4 bv = *(const float4*)(bias + (lane & 31) * 4);
    float bb4[4] = {bv.x, bv.y, bv.z, bv.w};
    f4 r;
    r[0] = dn * a[0] + sw * b2f(mv[0]) + bb4[0];
    r[1] = dn * a[1] + sw * b2f(mv[1]) + bb4[1];
    r[2] = dn * a[2] + sw * b2f(mv[2]) + bb4[2];
    r[3] = dn * a[3] + sw * b2f(mv[3]) + bb4[3];
    float* dstp = (lane < 32 ? Hpos : Hneg) + (size_t)wid * 128 + (lane & 31) * 4;
    __builtin_nontemporal_store(r, (f4*)dstp);
}

// ----------------------------- tail kernels ---------------------------------
__global__ void k_colsum(const float* __restrict__ H, float* __restrict__ colsum, int n) {
    int c = threadIdx.x & 127, half = threadIdx.x >> 7;
    float acc = 0.f;
    for (int r = blockIdx.x * 2 + half; r < n; r += gridDim.x * 2)
        acc += H[(size_t)r * 128 + c];
    __shared__ float sh[256];
    sh[threadIdx.x] = acc;
    __syncthreads();
    if (half == 0) atomicAdd(&colsum[c], sh[c] + sh[c + 128]);
}

__global__ void k_summary(const float* __restrict__ colsum, const float* __restrict__ Wb,
                          float* __restrict__ t, int n) {
    __shared__ float s_sh[128];
    int d = threadIdx.x;
    float m = colsum[d] / (float)n;
    s_sh[d] = 1.0f / (1.0f + expf(-m));
    __syncthreads();
    float acc = 0.f;
    for (int e = 0; e < 128; ++e) acc += Wb[d * 128 + e] * s_sh[e];
    t[d] = acc;
}

// merged disc over 2N nodes: wid<n -> Hpos, else Hneg
__global__ void k_disc(const float* __restrict__ Hpos, const float* __restrict__ Hneg,
                       const float* __restrict__ t, const float* __restrict__ bb,
                       float* __restrict__ out, int n) {
    int wid = (blockIdx.x * blockDim.x + threadIdx.x) >> 6;
    int lane = threadIdx.x & 63;
    if (wid >= 2 * n) return;
    const float* row = (wid < n) ? (Hpos + (size_t)wid * 128)
                                 : (Hneg + (size_t)(wid - n) * 128);
    float p = row[lane] * t[lane] + row[lane + 64] * t[lane + 64];
#pragma unroll
    for (int off = 32; off > 0; off >>= 1) p += __shfl_down(p, off);
    if (lane == 0) out[wid] = p + bb[0];
}

// ---------------------------------------------------------------------------
extern "C" void kernel_launch(void* const* d_in, const int* in_sizes, int n_in,
                              void* d_out, int out_size, void* d_ws, size_t ws_size,
                              hipStream_t stream) {
    const float* x    = (const float*)d_in[0];
    const int*   ei   = (const int*)d_in[1];
    const int*   perm = (const int*)d_in[2];
    const float* W1   = (const float*)d_in[3];
    const float* b1   = (const float*)d_in[4];
    const float* W2   = (const float*)d_in[5];
    const float* b2   = (const float*)d_in[6];
    const float* Wb   = (const float*)d_in[7];
    const float* bb   = (const float*)d_in[8];
    float* out = (float*)d_out;

    const int N   = in_sizes[2];
    const int E   = in_sizes[1] / 2;
    const int IN  = in_sizes[0] / N;   // 256
    const int HID = in_sizes[4];       // 256
    const int OUT = in_sizes[6];       // 128
    const int* src = ei;
    const int* dst = ei + E;

    char* p = (char*)d_ws;
    auto alloc = [&](size_t bytes) -> void* {
        void* r = (void*)p;
        p += (bytes + 255) & ~(size_t)255;
        return r;
    };
    int*   deg    = (int*)alloc((size_t)N * 4);
    int*   cursor = (int*)alloc((size_t)N * 4);
    float* colsum = (float*)alloc(128 * 4);
    size_t zlen   = (size_t)(p - (char*)deg);
    int*   rowptr = (int*)alloc((size_t)(N + 1) * 4);
    int*   bsum   = (int*)alloc(128 * 4);
    int*   boff   = (int*)alloc(128 * 4);
    int*   csr    = (int*)alloc((size_t)E * 4);
    int*   pcsr   = (int*)alloc((size_t)E * 4);
    float* dinv   = (float*)alloc((size_t)N * 4);
    float* tvec   = (float*)alloc(128 * 4);
    unsigned short* W1thi = (unsigned short*)alloc((size_t)IN * HID * 2);
    unsigned short* W1tlo = (unsigned short*)alloc((size_t)IN * HID * 2);
    unsigned short* W2thi = (unsigned short*)alloc((size_t)HID * OUT * 2);
    unsigned short* W2tlo = (unsigned short*)alloc((size_t)HID * OUT * 2);
    // P0: X split planes; reused as neg layer-1 split planes after GEMM1
    unsigned short* Xhi = (unsigned short*)alloc((size_t)N * IN * 2);
    unsigned short* Xlo = (unsigned short*)alloc((size_t)N * IN * 2);
    // P1: G1 (GEMM1 bf16 out); later the interleaved G2 [N][256]
    unsigned short* G1 = (unsigned short*)alloc((size_t)N * HID * 2);
    // P2: pos layer-1 split planes; later Hpos / Hneg (f32, N*OUT each)
    unsigned short* Bphi = (unsigned short*)alloc((size_t)N * HID * 2);
    unsigned short* Bplo = (unsigned short*)alloc((size_t)N * HID * 2);

    unsigned short* Bnhi = Xhi;                  // X dead after GEMM1
    unsigned short* Bnlo = Xlo;
    unsigned short* G2 = G1;                     // G1 dead after k_agg2
    float* Hpos = (float*)Bphi;                  // B planes dead after GEMM2
    float* Hneg = (float*)Bplo;

    hipMemsetAsync(deg, 0, zlen, stream);

    int eb = (E + 255) / 256;
    int nb = (N + 255) / 256;
    int nscan = (N + 1023) / 1024;
    k_degree<<<eb, 256, 0, stream>>>(dst, deg, E);
    k_dinv<<<nb, 256, 0, stream>>>(deg, dinv, rowptr, N, E);
    k_scanA<<<nscan, 256, 0, stream>>>(deg, rowptr, bsum, N);
    k_scanB<<<1, 128, 0, stream>>>(bsum, boff, nscan);
    k_scanC<<<nscan, 256, 0, stream>>>(rowptr, boff, N);
    k_fill<<<eb, 256, 0, stream>>>(src, dst, perm, rowptr, cursor, csr, pcsr, E);

    long n4 = (long)N * IN / 4;
    k_split<<<(int)((n4 + 255) / 256), 256, 0, stream>>>(x, Xhi, Xlo, n4);
    k_wsplitT<<<(IN * HID + 255) / 256, 256, 0, stream>>>(W1, W1thi, W1tlo, IN, HID);
    k_wsplitT<<<(HID * OUT + 255) / 256, 256, 0, stream>>>(W2, W2thi, W2tlo, HID, OUT);

    int mblk = (N + 127) / 128;
    int aggb = (N + 3) / 4;

    // layer 1: one GEMM serves pos and neg (row permutation commutes)
    k_gemm_mfma<<<dim3(HID / 128, mblk, 1), 256, 0, stream>>>(
        Xhi, Xlo, Xhi, Xlo, W1thi, W1tlo, G1, N, IN, HID, HID, 0);
    k_agg2<<<aggb, 256, 0, stream>>>(G1, rowptr, csr, pcsr, perm, dinv, b1,
                                     Bphi, Bplo, Bnhi, Bnlo, N);

    // layer 2: one GEMM launch, z=0 pos -> G2 cols 0..127, z=1 neg -> 128..255
    k_gemm_mfma<<<dim3(OUT / 128, mblk, 2), 256, 0, stream>>>(
        Bphi, Bplo, Bnhi, Bnlo, W2thi, W2tlo, G2, N, HID, OUT, HID, OUT);
    k_agg128m<<<aggb, 256, 0, stream>>>(G2, rowptr, csr, dinv, b2, Hpos, Hneg, N);

    // summary + discriminator
    k_colsum<<<256, 256, 0, stream>>>(Hpos, colsum, N);
    k_summary<<<1, 128, 0, stream>>>(colsum, Wb, tvec, N);
    int db = (int)(((size_t)N * 2 * 64 + 255) / 256);
    k_disc<<<db, 256, 0, stream>>>(Hpos, Hneg, tvec, bb, out, N);
}

// Round 7
// 924.752 us; speedup vs baseline: 1.8963x; 1.0697x over previous
//
#include <hip/hip_runtime.h>

// ---------------------------------------------------------------------------
// DGI forward, round 7 (round-6 resubmit; GPU acquisition timed out):
//  - pre-scaled gather tables: T[i]=dinv[i]*hw[i], U[i]=dinv[i]*hw[perm[i]]
//    interleaved as TU [N][512] bf16 -> aggregation is pure adds over ONE
//    index stream, one 16B load/lane/edge; self-term = same row
//  - GEMM1 epilogue writes T half + scatters U half via pinv (no build pass)
//  - layer-2 table G2 pre-scaled by dinv in GEMM2 epilogue (same trick)
//  - 2-pass split-bf16 GEMM: A_hi x (B_hi + B_lo); A lo-planes eliminated
// ---------------------------------------------------------------------------

typedef __attribute__((ext_vector_type(8))) short bh8;     // 8 bf16 (4 VGPR)
typedef __attribute__((ext_vector_type(4))) float f4;      // MFMA acc / NT f32x4
typedef __attribute__((ext_vector_type(4))) unsigned short u16x4;
typedef __attribute__((ext_vector_type(8))) unsigned short u16x8;

#define AS1 __attribute__((address_space(1)))
#define AS3 __attribute__((address_space(3)))

__device__ __forceinline__ unsigned short f2b(float f) {   // f32 -> bf16 RTNE
    unsigned int u = __float_as_uint(f);
    unsigned int r = (u + 0x7FFFu + ((u >> 16) & 1u)) >> 16;
    return (unsigned short)r;
}
__device__ __forceinline__ float b2f(unsigned short h) {
    return __uint_as_float(((unsigned int)h) << 16);
}

// ----------------------------- CSR build -----------------------------------
__global__ void k_degree(const int* __restrict__ dst, int* __restrict__ deg, int E) {
    int e = blockIdx.x * blockDim.x + threadIdx.x;
    if (e < E) atomicAdd(&deg[dst[e]], 1);
}

// dinv + inverse permutation + rowptr tail
__global__ void k_dinv(const int* __restrict__ deg, const int* __restrict__ perm,
                       float* __restrict__ dinv, int* __restrict__ pinv,
                       int* __restrict__ rowptr, int N, int E) {
    int n = blockIdx.x * blockDim.x + threadIdx.x;
    if (n < N) {
        dinv[n] = 1.0f / sqrtf(1.0f + (float)deg[n]);
        pinv[perm[n]] = n;
    }
    if (n == 0) rowptr[N] = E;
}

__global__ void k_scanA(const int* __restrict__ in, int* __restrict__ out,
                        int* __restrict__ bsum, int n) {
    __shared__ int sh[256];
    int t = threadIdx.x;
    int base = blockIdx.x * 1024 + t * 4;
    int v[4];
#pragma unroll
    for (int j = 0; j < 4; ++j) v[j] = (base + j < n) ? in[base + j] : 0;
    int s = v[0] + v[1] + v[2] + v[3];
    sh[t] = s;
    __syncthreads();
    for (int off = 1; off < 256; off <<= 1) {
        int u = (t >= off) ? sh[t - off] : 0;
        __syncthreads();
        sh[t] += u;
        __syncthreads();
    }
    int excl = sh[t] - s;
    if (t == 255) bsum[blockIdx.x] = sh[255];
    int run = excl;
#pragma unroll
    for (int j = 0; j < 4; ++j) {
        if (base + j < n) out[base + j] = run;
        run += v[j];
    }
}

__global__ void k_scanB(const int* __restrict__ bsum, int* __restrict__ boff, int nb) {
    __shared__ int sh[128];
    int t = threadIdx.x;
    int v = (t < nb) ? bsum[t] : 0;
    sh[t] = v;
    __syncthreads();
    for (int off = 1; off < 128; off <<= 1) {
        int u = (t >= off) ? sh[t - off] : 0;
        __syncthreads();
        sh[t] += u;
        __syncthreads();
    }
    boff[t] = sh[t] - v;
}

__global__ void k_scanC(int* __restrict__ out, const int* __restrict__ boff, int n) {
    int t = threadIdx.x;
    int base = blockIdx.x * 1024 + t * 4;
    int add = boff[blockIdx.x];
#pragma unroll
    for (int j = 0; j < 4; ++j)
        if (base + j < n) out[base + j] += add;
}

__global__ void k_fill(const int* __restrict__ src, const int* __restrict__ dst,
                       const int* __restrict__ rowptr, int* __restrict__ cursor,
                       int* __restrict__ csr, int E) {
    int e = blockIdx.x * blockDim.x + threadIdx.x;
    if (e >= E) return;
    int d = dst[e];
    int p = rowptr[d] + atomicAdd(&cursor[d], 1);
    csr[p] = src[e];
}

// ------------------------- f32 -> bf16 (hi only) ----------------------------
__global__ void k_split(const float* __restrict__ in, unsigned short* __restrict__ hi,
                        long n4) {
    long i = (long)blockIdx.x * blockDim.x + threadIdx.x;
    if (i >= n4) return;
    float4 v = ((const float4*)in)[i];
    float f[4] = {v.x, v.y, v.z, v.w};
    u16x4 h;
#pragma unroll
    for (int j = 0; j < 4; ++j) h[j] = f2b(f[j]);
    ((u16x4*)hi)[i] = h;
}

// W [K][Nc] f32 -> Wt_hi/lo [Nc][K] bf16 (transpose + split, both planes)
__global__ void k_wsplitT(const float* __restrict__ W, unsigned short* __restrict__ thi,
                          unsigned short* __restrict__ tlo, int K, int Nc) {
    int t = blockIdx.x * blockDim.x + threadIdx.x;
    if (t >= K * Nc) return;
    int k = t / Nc, n = t % Nc;
    float f = W[t];
    unsigned short hb = f2b(f);
    thi[n * K + k] = hb;
    tlo[n * K + k] = f2b(f - b2f(hb));
}

// ------------- 2-pass split-bf16 MFMA GEMM (C = A@B), fused epilogues -------
// A plane [M][K] bf16 (hi only; blockIdx.z picks set 0/1), B [NcB][K] hi+lo.
// MODE 1: write TU table: TU[r][bcol+c]           = dinv[r]  * acc
//                         TU[pinv[r]][256+bcol+c] = dinv[pinv[r]] * acc
// MODE 2: write C[r*ldC + z*colz + bcol + c] = dinv[r] * acc
template <int MODE>
__global__ __launch_bounds__(256, 2) void k_gemm_mfma(
        const unsigned short* __restrict__ Ahi0, const unsigned short* __restrict__ Ahi1,
        const unsigned short* __restrict__ Bhi, const unsigned short* __restrict__ Blo,
        unsigned short* __restrict__ C, const float* __restrict__ dinv,
        const int* __restrict__ pinv, int M, int K, int NcB, int ldC, int colz) {
    __shared__ short lds[3][128 * 32];          // planes: A, Bhi, Blo (24 KB)
    const int tid  = threadIdx.x;
    const int lane = tid & 63;
    const int w    = tid >> 6;                  // wave 0..3
    const int wr   = w >> 1, wc = w & 1;
    const int row0 = blockIdx.y * 128;
    const int bcol = blockIdx.x * 128;          // col within B table
    const unsigned short* Ahi = blockIdx.z ? Ahi1 : Ahi0;

    // staging: w0 -> A slabs 0-3, w3 -> A slabs 4-7, w1 -> Bhi, w2 -> Blo
    const unsigned short* sp = (w == 1) ? Bhi : (w == 2) ? Blo : Ahi;
    const int  plane = (w == 1) ? 1 : (w == 2) ? 2 : 0;
    const int  slab0 = (w == 3) ? 4 : 0;
    const int  nslab = (w == 0 || w == 3) ? 4 : 8;
    const int  base0 = (w == 1 || w == 2) ? bcol : row0;
    const int  lim   = (w == 1 || w == 2) ? (NcB - 1) : (M - 1);
    const int  rsub  = lane >> 2;               // 0..15 row within slab
    const int  clin  = lane & 3;                // 16B chunk within 64B row

    f4 acc[4][4] = {};

    for (int k0 = 0; k0 < K; k0 += 32) {
        __syncthreads();
        for (int s = 0; s < nslab; ++s) {
            int slab = slab0 + s;
            int r = slab * 16 + rsub;
            int g = base0 + r;
            if (g > lim) g = lim;
            const unsigned short* srcp = sp + (size_t)g * K + k0 + clin * 8;
            __builtin_amdgcn_global_load_lds((const AS1 void*)srcp,
                                             (AS3 void*)&lds[plane][slab * 512], 16, 0, 0);
        }
        __syncthreads();

        bh8 ah[4], bh_[4], bl[4];
        const int fr = lane & 15;
        const int fc = (lane >> 4) * 8;
#pragma unroll
        for (int m = 0; m < 4; ++m)
            ah[m] = *(const bh8*)&lds[0][(wr * 64 + m * 16 + fr) * 32 + fc];
#pragma unroll
        for (int n = 0; n < 4; ++n) {
            int off = (wc * 64 + n * 16 + fr) * 32 + fc;
            bh_[n] = *(const bh8*)&lds[1][off];
            bl[n]  = *(const bh8*)&lds[2][off];
        }
#pragma unroll
        for (int m = 0; m < 4; ++m)
#pragma unroll
            for (int n = 0; n < 4; ++n)
                acc[m][n] = __builtin_amdgcn_mfma_f32_16x16x32_bf16(ah[m], bh_[n], acc[m][n], 0, 0, 0);
#pragma unroll
        for (int m = 0; m < 4; ++m)
#pragma unroll
            for (int n = 0; n < 4; ++n)
                acc[m][n] = __builtin_amdgcn_mfma_f32_16x16x32_bf16(ah[m], bl[n], acc[m][n], 0, 0, 0);
    }

    // C/D layout: col=lane&15, row=(lane>>4)*4+reg
    const int cr = (lane >> 4) * 4;
    const int cc = lane & 15;
#pragma unroll
    for (int m = 0; m < 4; ++m) {
        int r0 = row0 + wr * 64 + m * 16 + cr;
#pragma unroll
        for (int j = 0; j < 4; ++j) {
            int r = r0 + j;
            if (r >= M) continue;
            if constexpr (MODE == 1) {
                float sr = dinv[r];
                int   ur = pinv[r];
                float su = dinv[ur];
#pragma unroll
                for (int n = 0; n < 4; ++n) {
                    int c = bcol + wc * 64 + n * 16 + cc;
                    C[(size_t)r  * 512 + c]       = f2b(sr * acc[m][n][j]);
                    C[(size_t)ur * 512 + 256 + c] = f2b(su * acc[m][n][j]);
                }
            } else {
                float sr = dinv[r];
                int cbase = blockIdx.z * colz + bcol;
#pragma unroll
                for (int n = 0; n < 4; ++n) {
                    int c = cbase + wc * 64 + n * 16 + cc;
                    C[(size_t)r * ldC + c] = f2b(sr * acc[m][n][j]);
                }
            }
        }
    }
}

// ---- layer-1 aggregate over TU [N][512]: pure adds, one index stream -------
// lanes 0..31 -> pos (T half), lanes 32..63 -> neg (U half); 8 feats/lane.
__global__ __launch_bounds__(256) void k_aggTU(
        const unsigned short* __restrict__ TU, const int* __restrict__ rowptr,
        const int* __restrict__ csr, const float* __restrict__ dinv,
        const float* __restrict__ bias,
        unsigned short* __restrict__ Bp, unsigned short* __restrict__ Bn, int n) {
    int wid = (blockIdx.x * blockDim.x + threadIdx.x) >> 6;
    int lane = threadIdx.x & 63;
    if (wid >= n) return;
    int beg = rowptr[wid], end = rowptr[wid + 1];
    int off = lane * 8;                          // elem offset within 512-row
    float a[8] = {0.f, 0.f, 0.f, 0.f, 0.f, 0.f, 0.f, 0.f};
    int e = beg;
    for (; e + 3 < end; e += 4) {
        int s0 = csr[e], s1 = csr[e + 1], s2 = csr[e + 2], s3 = csr[e + 3];
        u16x8 v0 = *(const u16x8*)(TU + (size_t)s0 * 512 + off);
        u16x8 v1 = *(const u16x8*)(TU + (size_t)s1 * 512 + off);
        u16x8 v2 = *(const u16x8*)(TU + (size_t)s2 * 512 + off);
        u16x8 v3 = *(const u16x8*)(TU + (size_t)s3 * 512 + off);
#pragma unroll
        for (int j = 0; j < 8; ++j)
            a[j] += (b2f(v0[j]) + b2f(v1[j])) + (b2f(v2[j]) + b2f(v3[j]));
    }
    for (; e < end; ++e) {
        int s0 = csr[e];
        u16x8 v0 = *(const u16x8*)(TU + (size_t)s0 * 512 + off);
#pragma unroll
        for (int j = 0; j < 8; ++j) a[j] += b2f(v0[j]);
    }
    // self-term row (covers both halves)
    u16x8 vs = *(const u16x8*)(TU + (size_t)wid * 512 + off);
#pragma unroll
    for (int j = 0; j < 8; ++j) a[j] += b2f(vs[j]);

    float dn = dinv[wid];
    int f0 = (lane & 31) * 8;
    float4 bv0 = *(const float4*)(bias + f0);
    float4 bv1 = *(const float4*)(bias + f0 + 4);
    float bb8[8] = {bv0.x, bv0.y, bv0.z, bv0.w, bv1.x, bv1.y, bv1.z, bv1.w};
    u16x8 o;
#pragma unroll
    for (int j = 0; j < 8; ++j)
        o[j] = f2b(fmaxf(dn * a[j] + bb8[j], 0.f));
    unsigned short* dstp = (lane < 32 ? Bp : Bn) + (size_t)wid * 256 + f0;
    __builtin_nontemporal_store(o, (u16x8*)dstp);
}

// ---- layer-2 aggregate over pre-scaled G2 [N][256] = [pos|neg] -------------
__global__ __launch_bounds__(256) void k_aggT2(
        const unsigned short* __restrict__ G2, const int* __restrict__ rowptr,
        const int* __restrict__ csr, const float* __restrict__ dinv,
        const float* __restrict__ bias, float* __restrict__ Hpos,
        float* __restrict__ Hneg, int n) {
    int wid = (blockIdx.x * blockDim.x + threadIdx.x) >> 6;
    int lane = threadIdx.x & 63;
    if (wid >= n) return;
    int beg = rowptr[wid], end = rowptr[wid + 1];
    int off = lane * 4;
    float a[4] = {0.f, 0.f, 0.f, 0.f};
    int e = beg;
    for (; e + 3 < end; e += 4) {
        int s0 = csr[e], s1 = csr[e + 1], s2 = csr[e + 2], s3 = csr[e + 3];
        u16x4 v0 = *(const u16x4*)(G2 + (size_t)s0 * 256 + off);
        u16x4 v1 = *(const u16x4*)(G2 + (size_t)s1 * 256 + off);
        u16x4 v2 = *(const u16x4*)(G2 + (size_t)s2 * 256 + off);
        u16x4 v3 = *(const u16x4*)(G2 + (size_t)s3 * 256 + off);
#pragma unroll
        for (int j = 0; j < 4; ++j)
            a[j] += (b2f(v0[j]) + b2f(v1[j])) + (b2f(v2[j]) + b2f(v3[j]));
    }
    for (; e < end; ++e) {
        int s0 = csr[e];
        u16x4 v0 = *(const u16x4*)(G2 + (size_t)s0 * 256 + off);
#pragma unroll
        for (int j = 0; j < 4; ++j) a[j] += b2f(v0[j]);
    }
    u16x4 vs = *(const u16x4*)(G2 + (size_t)wid * 256 + off);
#pragma unroll
    for (int j = 0; j < 4; ++j) a[j] += b2f(vs[j]);

    float dn = dinv[wid];
    int f0 = (lane & 31) * 4;
    float4 bv = *(const float4*)(bias + f0);
    float bb4[4] = {bv.x, bv.y, bv.z, bv.w};
    f4 r;
#pragma unroll
    for (int j = 0; j < 4; ++j) r[j] = dn * a[j] + bb4[j];
    float* dstp = (lane < 32 ? Hpos : Hneg) + (size_t)wid * 128 + f0;
    __builtin_nontemporal_store(r, (f4*)dstp);
}

// ----------------------------- tail kernels ---------------------------------
__global__ void k_colsum(const float* __restrict__ H, float* __restrict__ colsum, int n) {
    int c = threadIdx.x & 127, half = threadIdx.x >> 7;
    float acc = 0.f;
    for (int r = blockIdx.x * 2 + half; r < n; r += gridDim.x * 2)
        acc += H[(size_t)r * 128 + c];
    __shared__ float sh[256];
    sh[threadIdx.x] = acc;
    __syncthreads();
    if (half == 0) atomicAdd(&colsum[c], sh[c] + sh[c + 128]);
}

__global__ void k_summary(const float* __restrict__ colsum, const float* __restrict__ Wb,
                          float* __restrict__ t, int n) {
    __shared__ float s_sh[128];
    int d = threadIdx.x;
    float m = colsum[d] / (float)n;
    s_sh[d] = 1.0f / (1.0f + expf(-m));
    __syncthreads();
    float acc = 0.f;
    for (int e = 0; e < 128; ++e) acc += Wb[d * 128 + e] * s_sh[e];
    t[d] = acc;
}

// merged disc over 2N nodes: wid<n -> Hpos, else Hneg
__global__ void k_disc(const float* __restrict__ Hpos, const float* __restrict__ Hneg,
                       const float* __restrict__ t, const float* __restrict__ bb,
                       float* __restrict__ out, int n) {
    int wid = (blockIdx.x * blockDim.x + threadIdx.x) >> 6;
    int lane = threadIdx.x & 63;
    if (wid >= 2 * n) return;
    const float* row = (wid < n) ? (Hpos + (size_t)wid * 128)
                                 : (Hneg + (size_t)(wid - n) * 128);
    float p = row[lane] * t[lane] + row[lane + 64] * t[lane + 64];
#pragma unroll
    for (int off = 32; off > 0; off >>= 1) p += __shfl_down(p, off);
    if (lane == 0) out[wid] = p + bb[0];
}

// ---------------------------------------------------------------------------
extern "C" void kernel_launch(void* const* d_in, const int* in_sizes, int n_in,
                              void* d_out, int out_size, void* d_ws, size_t ws_size,
                              hipStream_t stream) {
    const float* x    = (const float*)d_in[0];
    const int*   ei   = (const int*)d_in[1];
    const int*   perm = (const int*)d_in[2];
    const float* W1   = (const float*)d_in[3];
    const float* b1   = (const float*)d_in[4];
    const float* W2   = (const float*)d_in[5];
    const float* b2   = (const float*)d_in[6];
    const float* Wb   = (const float*)d_in[7];
    const float* bb   = (const float*)d_in[8];
    float* out = (float*)d_out;

    const int N   = in_sizes[2];
    const int E   = in_sizes[1] / 2;
    const int IN  = in_sizes[0] / N;   // 256
    const int HID = in_sizes[4];       // 256
    const int OUT = in_sizes[6];       // 128
    const int* src = ei;
    const int* dst = ei + E;

    char* p = (char*)d_ws;
    auto alloc = [&](size_t bytes) -> void* {
        void* r = (void*)p;
        p += (bytes + 255) & ~(size_t)255;
        return r;
    };
    int*   deg    = (int*)alloc((size_t)N * 4);
    int*   cursor = (int*)alloc((size_t)N * 4);
    float* colsum = (float*)alloc(128 * 4);
    size_t zlen   = (size_t)(p - (char*)deg);
    int*   rowptr = (int*)alloc((size_t)(N + 1) * 4);
    int*   bsum   = (int*)alloc(128 * 4);
    int*   boff   = (int*)alloc(128 * 4);
    int*   csr    = (int*)alloc((size_t)E * 4);
    int*   pinv   = (int*)alloc((size_t)N * 4);
    float* dinv   = (float*)alloc((size_t)N * 4);
    float* tvec   = (float*)alloc(128 * 4);
    unsigned short* W1thi = (unsigned short*)alloc((size_t)IN * HID * 2);
    unsigned short* W1tlo = (unsigned short*)alloc((size_t)IN * HID * 2);
    unsigned short* W2thi = (unsigned short*)alloc((size_t)HID * OUT * 2);
    unsigned short* W2tlo = (unsigned short*)alloc((size_t)HID * OUT * 2);
    unsigned short* Xhi = (unsigned short*)alloc((size_t)N * IN * 2);   // 51 MB
    unsigned short* TU  = (unsigned short*)alloc((size_t)N * 512 * 2);  // 102 MB
    unsigned short* Bp  = (unsigned short*)alloc((size_t)N * HID * 2);  // 51 MB
    unsigned short* Bn  = (unsigned short*)alloc((size_t)N * HID * 2);  // 51 MB

    unsigned short* G2 = Xhi;                    // Xhi dead after GEMM1
    float* Hpos = (float*)TU;                    // TU dead after k_aggTU
    float* Hneg = (float*)(TU + (size_t)N * 256);

    hipMemsetAsync(deg, 0, zlen, stream);

    int eb = (E + 255) / 256;
    int nb = (N + 255) / 256;
    int nscan = (N + 1023) / 1024;
    k_degree<<<eb, 256, 0, stream>>>(dst, deg, E);
    k_dinv<<<nb, 256, 0, stream>>>(deg, perm, dinv, pinv, rowptr, N, E);
    k_scanA<<<nscan, 256, 0, stream>>>(deg, rowptr, bsum, N);
    k_scanB<<<1, 128, 0, stream>>>(bsum, boff, nscan);
    k_scanC<<<nscan, 256, 0, stream>>>(rowptr, boff, N);
    k_fill<<<eb, 256, 0, stream>>>(src, dst, rowptr, cursor, csr, E);

    long n4 = (long)N * IN / 4;
    k_split<<<(int)((n4 + 255) / 256), 256, 0, stream>>>(x, Xhi, n4);
    k_wsplitT<<<(IN * HID + 255) / 256, 256, 0, stream>>>(W1, W1thi, W1tlo, IN, HID);
    k_wsplitT<<<(HID * OUT + 255) / 256, 256, 0, stream>>>(W2, W2thi, W2tlo, HID, OUT);

    int mblk = (N + 127) / 128;
    int aggb = (N + 3) / 4;

    // layer 1: GEMM (one pass serves pos+neg) -> fused scaled TU scatter
    k_gemm_mfma<1><<<dim3(HID / 128, mblk, 1), 256, 0, stream>>>(
        Xhi, Xhi, W1thi, W1tlo, TU, dinv, pinv, N, IN, HID, 512, 0);
    k_aggTU<<<aggb, 256, 0, stream>>>(TU, rowptr, csr, dinv, b1, Bp, Bn, N);

    // layer 2: z=0 pos -> G2 cols 0..127, z=1 neg -> 128..255 (pre-scaled)
    k_gemm_mfma<2><<<dim3(OUT / 128, mblk, 2), 256, 0, stream>>>(
        Bp, Bn, W2thi, W2tlo, G2, dinv, pinv, N, HID, OUT, HID, OUT);
    k_aggT2<<<aggb, 256, 0, stream>>>(G2, rowptr, csr, dinv, b2, Hpos, Hneg, N);

    // summary + discriminator
    k_colsum<<<256, 256, 0, stream>>>(Hpos, colsum, N);
    k_summary<<<1, 128, 0, stream>>>(colsum, Wb, tvec, N);
    int db = (int)(((size_t)N * 2 * 64 + 255) / 256);
    k_disc<<<db, 256, 0, stream>>>(Hpos, Hneg, tvec, bb, out, N);
}